// Round 9
// baseline (332.373 us; speedup 1.0000x reference)
//
#include <hip/hip_runtime.h>
#include <hip/hip_bf16.h>

#define HIDN   64
#define NHEADS 8
#define DHEAD  8
#define NLAY   2
#define BB     4
#define SS     12
#define NNODE  512
#define NEDGE  8192
#define XELEMS (BB * SS * NNODE * 3)      // 73728
#define ROWS   (BB * SS * NNODE)          // 24576
#define QSCALE 0.51006967f                // (1/sqrt(8)) * log2(e): exp(x)=exp2(x*log2e)

typedef unsigned short u16;
typedef unsigned int   u32;
typedef __attribute__((ext_vector_type(4))) float f4;   // indexable float4

__device__ __forceinline__ float b2f(u16 u) {
    union { u32 i; float f; } c; c.i = ((u32)u) << 16; return c.f;
}
// decode element i of a raw input tensor (fl=1 -> fp32, fl=0 -> bf16)
__device__ __forceinline__ float ld(const void* p, int i, int fl) {
    return fl ? ((const float*)p)[i] : b2f(((const u16*)p)[i]);
}

// -------- dtype detection FALLBACK (only if in_sizes is ambiguous) -----------
__global__ void detect_kernel(const u16* __restrict__ x, int* __restrict__ flag) {
    int i0 = blockIdx.x * 256 + threadIdx.x;
    int bad = 0;
    for (int i = i0; i < XELEMS; i += 64 * 256) {
        float v = fabsf(b2f(x[i]));
        if (!(v <= 100.f)) bad = 1;   // catches huge AND NaN
    }
    if (bad) atomicOr(flag, 1);       // flag=1 -> inputs are fp32
}

// ---------------- PREP mega-kernel: input_proj + weight packV2 + mask/CSR ----
// packV2 dest layout: wT[p][l][ph][ib][j][4]: element (i,j) at
// ph=i>>5, ib=(i>>2)&7, i2=i&3, addr = ph*6144 + ib*768 + j*4 + i2.
struct PrepArgs {
    const void* x; const void* Win; const void* bin; float* h;
    const void* Wq[2]; const void* bq[2];
    const void* Wk[2]; const void* bk[2];
    const void* Wv[2]; const void* bv[2];
    float* wT[2]; float* bp[2];
    const int* ei; int* row_ptr; u16* col_idx;
};
__global__ __launch_bounds__(512) void prep_kernel(PrepArgs a, const int* __restrict__ flagp) {
    __shared__ u32 msk[NNODE * 16];   // 32 KB (only used by last block)
    __shared__ int sc[512];
    int fl = (*flagp != 0);
    int bid = blockIdx.x;
    int tid = threadIdx.x;
    if (bid < 384) {
        // ---- input projection: 8 consecutive h elems per thread
        int base = (bid * 512 + tid) * 8;     // row*64 + j0
        int row = base >> 6, j0 = base & 63;
        float x0 = ld(a.x, row * 3, fl);
        float x1 = ld(a.x, row * 3 + 1, fl);
        float x2 = ld(a.x, row * 3 + 2, fl);
        float o[8];
#pragma unroll
        for (int jj = 0; jj < 8; ++jj) {
            int j = j0 + jj;
            o[jj] = ld(a.bin, j, fl) + x0 * ld(a.Win, j * 3, fl)
                  + x1 * ld(a.Win, j * 3 + 1, fl) + x2 * ld(a.Win, j * 3 + 2, fl);
        }
        *(float4*)&a.h[base]     = make_float4(o[0], o[1], o[2], o[3]);
        *(float4*)&a.h[base + 4] = make_float4(o[4], o[5], o[6], o[7]);
        return;
    }
    if (bid < 480) {
        // ---- weight packV2
        int u = (bid - 384) * 512 + tid;  // 0..49151
        int p = u / 24576;
        int rem = u - p * 24576;
        int l = rem / 12288;
        int t = rem - l * 12288;          // linear DEST index
        int ph = t / 6144;
        int r  = t - ph * 6144;
        int ib = r / 768;                 // 0..7
        int r2 = r - ib * 768;
        int j  = r2 >> 2;                 // 0..191
        int i2 = r2 & 3;
        int i  = ph * 32 + ib * 4 + i2;   // 0..63
        int cg = j >> 6, cc = j & 63;
        const void* W = (cg == 0) ? a.Wq[p] : (cg == 1) ? a.Wk[p] : a.Wv[p];
        a.wT[p][l * 12288 + t] = ld(W, l * 4096 + cc * 64 + i, fl);
        // ---- bias: first 768 u's cover 2p x 2l x 192
        if (u < 768) {
            int p2 = u / 384;
            int r3 = u - p2 * 384;
            int l2 = r3 / 192;
            int j2 = r3 - l2 * 192;
            int cg2 = j2 >> 6;
            const void* B = (cg2 == 0) ? a.bq[p2] : (cg2 == 1) ? a.bk[p2] : a.bv[p2];
            a.bp[p2][l2 * 192 + j2] = ld(B, l2 * 64 + (j2 & 63), fl);
        }
        return;
    }
    // ---- mask bitset (LDS) + CSR build, one 512-thread block
    for (int i = tid; i < NNODE * 16; i += 512) msk[i] = 0;
    __syncthreads();
    for (int e = tid; e < NEDGE; e += 512) {
        int r = a.ei[e];           // query row
        int m = a.ei[NEDGE + e];   // key col
        atomicOr(&msk[r * 16 + (m >> 5)], 1u << (m & 31));
    }
    __syncthreads();
    int n = tid;   // 0..511
    u32 w[16];
    int d = 0;
#pragma unroll
    for (int i = 0; i < 16; ++i) { w[i] = msk[n * 16 + i]; d += __popc(w[i]); }
    sc[n] = d;
    __syncthreads();
    for (int s = 1; s < 512; s <<= 1) {
        int v = (n >= s) ? sc[n - s] : 0;
        __syncthreads();
        sc[n] += v;
        __syncthreads();
    }
    int excl = sc[n] - d;
    a.row_ptr[n] = excl;
    if (n == 511) a.row_ptr[512] = sc[511];
    int base = excl;
#pragma unroll
    for (int i = 0; i < 16; ++i) {
        u32 m = w[i];
        while (m) {
            int b = __ffs(m) - 1;
            m &= m - 1;
            a.col_idx[base++] = (u16)(i * 32 + b);
        }
    }
}

// ---------------- FUSED spatial: qkv head-slice GEMM + sparse attention ------
// grid 768 = (pair = bs*8+hd) x (half); 256 threads.
// 16 chunks of 32 nodes: stage hT[i][nodeL] (transposed, conflict-free),
// GEMM K/V cols for head hd into Ks/Vs[512][8], q into qS[256][9] (xQSCALE).
// Then the proven sparse-CSR attention. GEMM i-order == qkv v5 -> bit-identical.
__global__ __launch_bounds__(256) void spat_fused_kernel(
    const float* __restrict__ h, const float* __restrict__ wT,
    const float* __restrict__ bias,
    const int* __restrict__ row_ptr, const u16* __restrict__ col_idx,
    float* __restrict__ h2) {
    __shared__ float hT[64][32];                   //  8 KB  [i][nodeLocal]
    __shared__ __align__(16) float Ks[NNODE][8];   // 16 KB
    __shared__ __align__(16) float Vs[NNODE][8];   // 16 KB
    __shared__ float qS[256][9];                   //  9 KB
    int bxx = blockIdx.x;
    int pair = bxx >> 1, half = bxx & 1;
    int bs = pair >> 3, hd = pair & 7;             // bs = b*S+s in [0,48)
    int t = threadIdx.x;
    const float* hsl = h + (long)bs * NNODE * HIDN;   // slice [512][64]

    // gemm thread mapping (fixed across chunks)
    int nodeL = t & 31;
    int g     = t >> 5;              // 0..7
    int kv    = g >> 2;              // 0:K 1:V
    int c2    = (g & 3) * 2;         // col pair base in [0,8)
    int jg    = 64 + kv * 64 + hd * 8 + c2;        // wT col for K/V
    int jq    = hd * 8 + (t & 7);                  // wT col for q
    float b0 = bias[jg], b1 = bias[jg + 1], bq = bias[jq];

    for (int c = 0; c < 16; ++c) {
        __syncthreads();   // prior chunk's hT readers done
        // stage hT (transposed): 2 f4 per thread, LDS writes conflict-free
#pragma unroll
        for (int k = 0; k < 2; ++k) {
            int fid = t + 256 * k;
            int nl2 = fid & 31, ic = fid >> 5;     // ic 0..15
            f4 hv = *(const f4*)(hsl + (c * 32 + nl2) * HIDN + ic * 4);
            hT[ic * 4 + 0][nl2] = hv[0];
            hT[ic * 4 + 1][nl2] = hv[1];
            hT[ic * 4 + 2][nl2] = hv[2];
            hT[ic * 4 + 3][nl2] = hv[3];
        }
        __syncthreads();
        // K/V gemm: 2 outputs per thread (node nodeL, cols c2, c2+1)
        float a0 = b0, a1 = b1;
#pragma unroll
        for (int ph = 0; ph < 2; ++ph)
#pragma unroll
            for (int ib = 0; ib < 8; ++ib) {
                f4 wA = *(const f4*)(wT + ph * 6144 + ib * 768 + jg * 4);
                f4 wB = *(const f4*)(wT + ph * 6144 + ib * 768 + (jg + 1) * 4);
#pragma unroll
                for (int ii = 0; ii < 4; ++ii) {
                    float hv = hT[ph * 32 + ib * 4 + ii][nodeL];
                    a0 += hv * wA[ii];
                    a1 += hv * wB[ii];
                }
            }
        int node = c * 32 + nodeL;
        if (kv == 0) { Ks[node][c2] = a0; Ks[node][c2 + 1] = a1; }
        else         { Vs[node][c2] = a0; Vs[node][c2 + 1] = a1; }
        // q gemm for chunks holding this half's queries: 1 output per thread
        if ((c >> 3) == half) {
            int qr = t >> 3;                       // within-chunk row 0..31
            float qa = bq;
#pragma unroll
            for (int ph = 0; ph < 2; ++ph)
#pragma unroll
                for (int ib = 0; ib < 8; ++ib) {
                    f4 wq = *(const f4*)(wT + ph * 6144 + ib * 768 + jq * 4);
#pragma unroll
                    for (int ii = 0; ii < 4; ++ii)
                        qa += hT[ph * 32 + ib * 4 + ii][qr] * wq[ii];
                }
            qS[(c & 7) * 32 + qr][t & 7] = qa * QSCALE;
        }
    }
    __syncthreads();
    // ---- sparse attention (verbatim structure from R8) ----
    int n = half * 256 + t;
    float4 qa = make_float4(qS[t][0], qS[t][1], qS[t][2], qS[t][3]);
    float4 qc = make_float4(qS[t][4], qS[t][5], qS[t][6], qS[t][7]);
    int e0 = row_ptr[n], e1 = row_ptr[n + 1];
    float l = 0.f;
    float o0=0.f,o1=0.f,o2=0.f,o3=0.f,o4=0.f,o5=0.f,o6=0.f,o7=0.f;
    for (int e = e0; e < e1; ++e) {
        int m = col_idx[e];
        float4 ka = *(const float4*)&Ks[m][0];
        float4 kc = *(const float4*)&Ks[m][4];
        float s = qa.x*ka.x + qa.y*ka.y + qa.z*ka.z + qa.w*ka.w
                + qc.x*kc.x + qc.y*kc.y + qc.z*kc.z + qc.w*kc.w;
        float p = exp2f(s);          // q prescaled by (1/sqrt8)*log2e
        l += p;
        float4 va = *(const float4*)&Vs[m][0];
        float4 vc = *(const float4*)&Vs[m][4];
        o0 += p*va.x; o1 += p*va.y; o2 += p*va.z; o3 += p*va.w;
        o4 += p*vc.x; o5 += p*vc.y; o6 += p*vc.z; o7 += p*vc.w;
    }
    if (e1 == e0) {                  // fully-masked row: uniform mean(V)
        for (int m = 0; m < NNODE; ++m) {
            o0 += Vs[m][0]; o1 += Vs[m][1]; o2 += Vs[m][2]; o3 += Vs[m][3];
            o4 += Vs[m][4]; o5 += Vs[m][5]; o6 += Vs[m][6]; o7 += Vs[m][7];
        }
        l = (float)NNODE;
    }
    float inv = 1.f / l;
    float* op = h2 + ((long)(bs * NNODE + n)) * HIDN + hd * 8;
    *(float4*)op       = make_float4(o0*inv, o1*inv, o2*inv, o3*inv);
    *(float4*)(op + 4) = make_float4(o4*inv, o5*inv, o6*inv, o7*inv);
}

// ---------------- FUSED temporal: full qkv GEMM + temporal attention ---------
// grid 512 = (b [4]) x (4-node chunk [128]); 384 threads.
// Stage 48 h2 rows transposed hT2[i][row]; v5-style GEMM (col = t%192,
// lane-consecutive packed-W f4 reads, broadcast h reads) into
// qkvS[3][12][32][9] (stride-9 conflict-free); then R8 temporal attention.
// GEMM i-order == v5; attention expression == R8 -> bit-identical.
__global__ __launch_bounds__(384) void temp_fused_kernel(
    const float* __restrict__ h2, const float* __restrict__ wT,
    const float* __restrict__ bias, float* __restrict__ h) {
    __shared__ float hT2[64][48];                  // 12 KB [i][row48]
    __shared__ float qkvS[3][SS][32][9];           // 40.5 KB
    int b  = blockIdx.x >> 7;
    int n0 = (blockIdx.x & 127) * 4;
    int t = threadIdx.x;
    // stage h2 rows (12 tt x 4 nl = 48 rows), transposed
#pragma unroll
    for (int k = 0; k < 2; ++k) {
        int fid = t + 384 * k;              // 0..767
        int rowL = fid % 48, ic = fid / 48; // ic 0..15
        int tt = rowL >> 2, nl = rowL & 3;
        f4 hv = *(const f4*)(h2 + ((long)((b * SS + tt) * NNODE) + n0 + nl) * HIDN + ic * 4);
        hT2[ic * 4 + 0][rowL] = hv[0];
        hT2[ic * 4 + 1][rowL] = hv[1];
        hT2[ic * 4 + 2][rowL] = hv[2];
        hT2[ic * 4 + 3][rowL] = hv[3];
    }
    __syncthreads();
    // qkv gemm: col = t%192, rowgroup = t/192 (wave-uniform), 24 rows each
    {
        int col = t % 192;
        int rg  = __builtin_amdgcn_readfirstlane(t / 192);
        float acc[24];
        float bb = bias[col];
#pragma unroll
        for (int rr = 0; rr < 24; ++rr) acc[rr] = bb;
#pragma unroll
        for (int ph = 0; ph < 2; ++ph)
#pragma unroll
            for (int ib = 0; ib < 8; ++ib) {
                f4 w4 = *(const f4*)(wT + ph * 6144 + ib * 768 + col * 4);
#pragma unroll
                for (int ii = 0; ii < 4; ++ii) {
                    int i = ph * 32 + ib * 4 + ii;
#pragma unroll
                    for (int q4 = 0; q4 < 6; ++q4) {
                        f4 hq = *(const f4*)&hT2[i][rg * 24 + q4 * 4];
                        acc[q4*4+0] += hq[0] * w4[ii];
                        acc[q4*4+1] += hq[1] * w4[ii];
                        acc[q4*4+2] += hq[2] * w4[ii];
                        acc[q4*4+3] += hq[3] * w4[ii];
                    }
                }
            }
        int tz = col >> 6, cc = col & 63;
        int hd = cc >> 3, dh = cc & 7;
#pragma unroll
        for (int rr = 0; rr < 24; ++rr) {
            int row = rg * 24 + rr;
            int tt = row >> 2, nl = row & 3;
            qkvS[tz][tt][nl * 8 + hd][dh] = acc[rr];
        }
    }
    __syncthreads();
    // ---- temporal attention (verbatim structure from R8 v3) ----
    int sq = t >> 5, rr = t & 31;      // rr = nl*8+hd
    int nl = rr >> 3, hd = rr & 7;
    const float* qd = &qkvS[0][sq][rr][0];
    float q0=qd[0],q1=qd[1],q2=qd[2],q3=qd[3],q4=qd[4],q5=qd[5],q6=qd[6],q7=qd[7];
    float s[SS];
#pragma unroll
    for (int tt = 0; tt < SS; ++tt) {
        const float* kd = &qkvS[1][tt][rr][0];
        s[tt] = (q0 * kd[0] + q1 * kd[1] + q2 * kd[2] + q3 * kd[3] +
                 q4 * kd[4] + q5 * kd[5] + q6 * kd[6] + q7 * kd[7]) * QSCALE;
    }
    float mx = s[0];
#pragma unroll
    for (int tt = 1; tt < SS; ++tt) mx = fmaxf(mx, s[tt]);
    float l = 0.f;
#pragma unroll
    for (int tt = 0; tt < SS; ++tt) { s[tt] = exp2f(s[tt] - mx); l += s[tt]; }
    float a0=0.f,a1=0.f,a2=0.f,a3=0.f,a4=0.f,a5=0.f,a6=0.f,a7=0.f;
#pragma unroll
    for (int tt = 0; tt < SS; ++tt) {
        const float* vd = &qkvS[2][tt][rr][0];
        float e = s[tt];
        a0 += e * vd[0]; a1 += e * vd[1]; a2 += e * vd[2]; a3 += e * vd[3];
        a4 += e * vd[4]; a5 += e * vd[5]; a6 += e * vd[6]; a7 += e * vd[7];
    }
    float inv = 1.f / l;
    float* op = h + ((long)((b * SS + sq) * NNODE) + n0 + nl) * HIDN + hd * 8;
    *(float4*)op       = make_float4(a0 * inv, a1 * inv, a2 * inv, a3 * inv);
    *(float4*)(op + 4) = make_float4(a4 * inv, a5 * inv, a6 * inv, a7 * inv);
}

// ---------------- output projection: h[:, S-1] @ raw WoutT + raw bout --------
__global__ void out_proj_kernel(const float* __restrict__ h, const void* __restrict__ W,
                                const void* __restrict__ b, void* __restrict__ out,
                                const int* __restrict__ flagp) {
    int fl = (*flagp != 0);
    int t = blockIdx.x * blockDim.x + threadIdx.x;
    if (t >= BB * NNODE * 3) return;
    int c  = t % 3;
    int bn = t / 3;
    int n  = bn & (NNODE - 1);
    int bb = bn >> 9;
    const float* hp = h + ((bb * SS + (SS - 1)) * NNODE + n) * HIDN;
    float a = ld(b, c, fl);
#pragma unroll
    for (int i = 0; i < HIDN; i += 4) {
        float4 h4 = *(const float4*)(hp + i);
        a += h4.x * ld(W, c * 64 + i,     fl) + h4.y * ld(W, c * 64 + i + 1, fl)
           + h4.z * ld(W, c * 64 + i + 2, fl) + h4.w * ld(W, c * 64 + i + 3, fl);
    }
    if (fl) ((float*)out)[t] = a;
    else    ((__hip_bfloat16*)out)[t] = __float2bfloat16(a);
}

extern "C" void kernel_launch(void* const* d_in, const int* in_sizes, int n_in,
                              void* d_out, int out_size, void* d_ws, size_t ws_size,
                              hipStream_t stream) {
    const int* ei = (const int*)d_in[1];

    float* ws = (float*)d_ws;
    int*   flag    = (int*)ws;                    // 64 floats reserved
    int*   row_ptr = (int*)(ws + 64);             // 513 ints (reserve 576)
    u16*   col_idx = (u16*)(ws + 640);            // 8192 u16 (4096 float slots)
    float* wTs   = ws + 640 + 4096;               // 2*12288
    float* wTt   = wTs + 24576;                   // 2*12288
    float* bsp   = wTt + 24576;                   // 2*192
    float* btp   = bsp + 384;                     // 2*192
    float* hbuf  = btp + 384;                     // ROWS*64
    float* h2buf = hbuf + ROWS * HIDN;            // ROWS*64 (spatial output)

    // dtype from host-visible byte sizes; runtime-detect only if ambiguous
    int flv = -1;
    if (in_sizes) {
        if (in_sizes[0] == XELEMS * 2) flv = 0;        // bf16
        else if (in_sizes[0] == XELEMS * 4) flv = 1;   // fp32
    }
    if (flv >= 0) {
        (void)hipMemsetAsync(flag, flv, sizeof(int), stream);
    } else {
        (void)hipMemsetAsync(flag, 0, sizeof(int), stream);
        detect_kernel<<<64, 256, 0, stream>>>((const u16*)d_in[0], flag);
    }

    PrepArgs pr;
    pr.x = d_in[0]; pr.Win = d_in[2]; pr.bin = d_in[3]; pr.h = hbuf;
    pr.Wq[0] = d_in[4];  pr.bq[0] = d_in[5];
    pr.Wk[0] = d_in[6];  pr.bk[0] = d_in[7];
    pr.Wv[0] = d_in[8];  pr.bv[0] = d_in[9];
    pr.Wq[1] = d_in[10]; pr.bq[1] = d_in[11];
    pr.Wk[1] = d_in[12]; pr.bk[1] = d_in[13];
    pr.Wv[1] = d_in[14]; pr.bv[1] = d_in[15];
    pr.wT[0] = wTs; pr.bp[0] = bsp;
    pr.wT[1] = wTt; pr.bp[1] = btp;
    pr.ei = ei; pr.row_ptr = row_ptr; pr.col_idx = col_idx;
    prep_kernel<<<384 + 96 + 1, 512, 0, stream>>>(pr, flag);

    for (int l = 0; l < NLAY; ++l) {
        spat_fused_kernel<<<BB * SS * NHEADS * 2, 256, 0, stream>>>(
            hbuf, wTs + l * 12288, bsp + l * 192, row_ptr, col_idx, h2buf);
        temp_fused_kernel<<<BB * (NNODE / 4), 384, 0, stream>>>(
            h2buf, wTt + l * 12288, btp + l * 192, hbuf);
    }
    out_proj_kernel<<<(BB * NNODE * 3 + 255) / 256, 256, 0, stream>>>(
        hbuf, d_in[16], d_in[17], d_out, flag);
}

// Round 10
// 233.183 us; speedup vs baseline: 1.4254x; 1.4254x over previous
//
#include <hip/hip_runtime.h>
#include <hip/hip_bf16.h>

#define HIDN   64
#define NHEADS 8
#define DHEAD  8
#define NLAY   2
#define BB     4
#define SS     12
#define NNODE  512
#define NEDGE  8192
#define XELEMS (BB * SS * NNODE * 3)      // 73728
#define ROWS   (BB * SS * NNODE)          // 24576
#define QSCALE 0.51006967f                // (1/sqrt(8)) * log2(e): exp(x)=exp2(x*log2e)

typedef unsigned short u16;
typedef unsigned int   u32;
typedef __attribute__((ext_vector_type(4))) float f4;   // indexable float4

__device__ __forceinline__ float b2f(u16 u) {
    union { u32 i; float f; } c; c.i = ((u32)u) << 16; return c.f;
}
// decode element i of a raw input tensor (fl=1 -> fp32, fl=0 -> bf16)
__device__ __forceinline__ float ld(const void* p, int i, int fl) {
    return fl ? ((const float*)p)[i] : b2f(((const u16*)p)[i]);
}

// -------- dtype detection FALLBACK (only if in_sizes is ambiguous) -----------
__global__ void detect_kernel(const u16* __restrict__ x, int* __restrict__ flag) {
    int i0 = blockIdx.x * 256 + threadIdx.x;
    int bad = 0;
    for (int i = i0; i < XELEMS; i += 64 * 256) {
        float v = fabsf(b2f(x[i]));
        if (!(v <= 100.f)) bad = 1;   // catches huge AND NaN
    }
    if (bad) atomicOr(flag, 1);       // flag=1 -> inputs are fp32
}

// ---------------- PREP mega-kernel: input_proj + weight packV2 + mask/CSR ----
// packV2 dest layout: wT[p][l][ph][ib][j][4]: element (i,j) at
// ph=i>>5, ib=(i>>2)&7, i2=i&3, addr = ph*6144 + ib*768 + j*4 + i2.
struct PrepArgs {
    const void* x; const void* Win; const void* bin; float* h;
    const void* Wq[2]; const void* bq[2];
    const void* Wk[2]; const void* bk[2];
    const void* Wv[2]; const void* bv[2];
    float* wT[2]; float* bp[2];
    const int* ei; int* row_ptr; u16* col_idx;
};
__global__ __launch_bounds__(512) void prep_kernel(PrepArgs a, const int* __restrict__ flagp) {
    __shared__ u32 msk[NNODE * 16];   // 32 KB (only used by last block)
    __shared__ int sc[512];
    int fl = (*flagp != 0);
    int bid = blockIdx.x;
    int tid = threadIdx.x;
    if (bid < 384) {
        // ---- input projection: 8 consecutive h elems per thread
        int base = (bid * 512 + tid) * 8;     // row*64 + j0
        int row = base >> 6, j0 = base & 63;
        float x0 = ld(a.x, row * 3, fl);
        float x1 = ld(a.x, row * 3 + 1, fl);
        float x2 = ld(a.x, row * 3 + 2, fl);
        float o[8];
#pragma unroll
        for (int jj = 0; jj < 8; ++jj) {
            int j = j0 + jj;
            o[jj] = ld(a.bin, j, fl) + x0 * ld(a.Win, j * 3, fl)
                  + x1 * ld(a.Win, j * 3 + 1, fl) + x2 * ld(a.Win, j * 3 + 2, fl);
        }
        *(float4*)&a.h[base]     = make_float4(o[0], o[1], o[2], o[3]);
        *(float4*)&a.h[base + 4] = make_float4(o[4], o[5], o[6], o[7]);
        return;
    }
    if (bid < 480) {
        // ---- weight packV2
        int u = (bid - 384) * 512 + tid;  // 0..49151
        int p = u / 24576;
        int rem = u - p * 24576;
        int l = rem / 12288;
        int t = rem - l * 12288;          // linear DEST index
        int ph = t / 6144;
        int r  = t - ph * 6144;
        int ib = r / 768;                 // 0..7
        int r2 = r - ib * 768;
        int j  = r2 >> 2;                 // 0..191
        int i2 = r2 & 3;
        int i  = ph * 32 + ib * 4 + i2;   // 0..63
        int cg = j >> 6, cc = j & 63;
        const void* W = (cg == 0) ? a.Wq[p] : (cg == 1) ? a.Wk[p] : a.Wv[p];
        a.wT[p][l * 12288 + t] = ld(W, l * 4096 + cc * 64 + i, fl);
        // ---- bias: first 768 u's cover 2p x 2l x 192
        if (u < 768) {
            int p2 = u / 384;
            int r3 = u - p2 * 384;
            int l2 = r3 / 192;
            int j2 = r3 - l2 * 192;
            int cg2 = j2 >> 6;
            const void* B = (cg2 == 0) ? a.bq[p2] : (cg2 == 1) ? a.bk[p2] : a.bv[p2];
            a.bp[p2][l2 * 192 + j2] = ld(B, l2 * 64 + (j2 & 63), fl);
        }
        return;
    }
    // ---- mask bitset (LDS) + CSR build, one 512-thread block
    for (int i = tid; i < NNODE * 16; i += 512) msk[i] = 0;
    __syncthreads();
    for (int e = tid; e < NEDGE; e += 512) {
        int r = a.ei[e];           // query row
        int m = a.ei[NEDGE + e];   // key col
        atomicOr(&msk[r * 16 + (m >> 5)], 1u << (m & 31));
    }
    __syncthreads();
    int n = tid;   // 0..511
    u32 w[16];
    int d = 0;
#pragma unroll
    for (int i = 0; i < 16; ++i) { w[i] = msk[n * 16 + i]; d += __popc(w[i]); }
    sc[n] = d;
    __syncthreads();
    for (int s = 1; s < 512; s <<= 1) {
        int v = (n >= s) ? sc[n - s] : 0;
        __syncthreads();
        sc[n] += v;
        __syncthreads();
    }
    int excl = sc[n] - d;
    a.row_ptr[n] = excl;
    if (n == 511) a.row_ptr[512] = sc[511];
    int base = excl;
#pragma unroll
    for (int i = 0; i < 16; ++i) {
        u32 m = w[i];
        while (m) {
            int b = __ffs(m) - 1;
            m &= m - 1;
            a.col_idx[base++] = (u16)(i * 32 + b);
        }
    }
}

// ---------------- fused q/k/v GEMM v6: zero LDS, 16-row tiles, grid 1536 -----
// 256 threads = (wave w -> 4-row group, lane c = col). W read directly from
// global (packV2 -> lane-consecutive float4, L1/L2-hot). h via wave-uniform
// scalar loads. Small acc footprint -> high waves/SIMD; grid 1536 = 6 blk/CU.
// FMA order over i identical to v5 -> bit-identical outputs.
__global__ __launch_bounds__(256, 8) void qkv_gemm_kernel(
    const float* __restrict__ h, const float* __restrict__ wT,
    const float* __restrict__ bias,
    float* __restrict__ q, float* __restrict__ k, float* __restrict__ v,
    int spatial_layout) {
    int t = threadIdx.x;
    int row0 = blockIdx.x * 16;
    int c = t & 63, w = t >> 6;
    int rowoff = __builtin_amdgcn_readfirstlane(w * 4);   // uniform row base
    const float* hw = h + (row0 + rowoff) * 64;
    float acc[3][4];
#pragma unroll
    for (int g = 0; g < 3; ++g) {
        float bb = bias[g * 64 + c];
#pragma unroll
        for (int rr = 0; rr < 4; ++rr) acc[g][rr] = bb;
    }
#pragma unroll
    for (int ph = 0; ph < 2; ++ph) {
#pragma unroll 2
        for (int i0 = 0; i0 < 32; i0 += 4) {
            f4 hv[4];
#pragma unroll
            for (int rr = 0; rr < 4; ++rr)
                hv[rr] = *(const f4*)(hw + rr * 64 + ph * 32 + i0);
            f4 wv[3];
#pragma unroll
            for (int g = 0; g < 3; ++g)
                wv[g] = *(const f4*)(wT + ph * 6144 + (((i0 >> 2) * 192) + g * 64 + c) * 4);
#pragma unroll
            for (int ii = 0; ii < 4; ++ii)
#pragma unroll
                for (int g = 0; g < 3; ++g) {
                    float wf = wv[g][ii];
#pragma unroll
                    for (int rr = 0; rr < 4; ++rr) acc[g][rr] += hv[rr][ii] * wf;
                }
        }
    }
    // ---- epilogue: lane-consecutive stores
    if (spatial_layout) {
        int bs = row0 >> 9, n0 = row0 & 511;
        int hd = c >> 3, dh = c & 7;
        long off = ((long)(bs * 8 + hd) * 512 + n0 + rowoff) * 8 + dh;
        float* qp = q + off;
        float* kp = k + off;
        float* vp = v + off;
#pragma unroll
        for (int rr = 0; rr < 4; ++rr) {
            qp[rr * 8] = acc[0][rr] * QSCALE;
            kp[rr * 8] = acc[1][rr];
            vp[rr * 8] = acc[2][rr];
        }
    } else {
        int off = (row0 + rowoff) * 64 + c;
        float* qp = q + off;
        float* kp = k + off;
        float* vp = v + off;
#pragma unroll
        for (int rr = 0; rr < 4; ++rr) {
            qp[rr * 64] = acc[0][rr];
            kp[rr * 64] = acc[1][rr];
            vp[rr * 64] = acc[2][rr];
        }
    }
}

// ---------------- spatial attention: SPARSE (avg degree 16/512) --------------
__global__ __launch_bounds__(256) void spatial_attn_kernel(
    const float* __restrict__ qh, const float* __restrict__ kh, const float* __restrict__ vh,
    const int* __restrict__ row_ptr, const u16* __restrict__ col_idx,
    float* __restrict__ h) {
    __shared__ __align__(16) float Ks[NNODE][8];   // 16 KB
    __shared__ __align__(16) float Vs[NNODE][8];   // 16 KB
    int bxx = blockIdx.x;
    int pair = bxx >> 1, halfq = bxx & 1;
    int bs = pair >> 3, hd = pair & 7;      // bs = b*S+s in [0,48)
    const float* kp = kh + pair * (NNODE * 8);
    const float* vp = vh + pair * (NNODE * 8);
    int t = threadIdx.x;
#pragma unroll
    for (int i = 0; i < 2; ++i) {
        int r = t + 256 * i;
        float4 k0 = *(const float4*)(kp + r * 8);
        float4 k1 = *(const float4*)(kp + r * 8 + 4);
        float4 v0 = *(const float4*)(vp + r * 8);
        float4 v1 = *(const float4*)(vp + r * 8 + 4);
        *(float4*)&Ks[r][0] = k0; *(float4*)&Ks[r][4] = k1;
        *(float4*)&Vs[r][0] = v0; *(float4*)&Vs[r][4] = v1;
    }
    __syncthreads();
    int n = halfq * 256 + t;
    const float* qp = qh + (pair * NNODE + n) * 8;
    float4 qa = *(const float4*)qp;
    float4 qc = *(const float4*)(qp + 4);
    int e0 = row_ptr[n], e1 = row_ptr[n + 1];
    float l = 0.f;
    float o0=0.f,o1=0.f,o2=0.f,o3=0.f,o4=0.f,o5=0.f,o6=0.f,o7=0.f;
    for (int e = e0; e < e1; ++e) {
        int m = col_idx[e];
        float4 ka = *(const float4*)&Ks[m][0];
        float4 kc = *(const float4*)&Ks[m][4];
        float s = qa.x*ka.x + qa.y*ka.y + qa.z*ka.z + qa.w*ka.w
                + qc.x*kc.x + qc.y*kc.y + qc.z*kc.z + qc.w*kc.w;
        float p = exp2f(s);          // q prescaled by (1/sqrt8)*log2e
        l += p;
        float4 va = *(const float4*)&Vs[m][0];
        float4 vc = *(const float4*)&Vs[m][4];
        o0 += p*va.x; o1 += p*va.y; o2 += p*va.z; o3 += p*va.w;
        o4 += p*vc.x; o5 += p*vc.y; o6 += p*vc.z; o7 += p*vc.w;
    }
    if (e1 == e0) {                  // fully-masked row: uniform mean(V)
        for (int m = 0; m < NNODE; ++m) {
            o0 += Vs[m][0]; o1 += Vs[m][1]; o2 += Vs[m][2]; o3 += Vs[m][3];
            o4 += Vs[m][4]; o5 += Vs[m][5]; o6 += Vs[m][6]; o7 += Vs[m][7];
        }
        l = (float)NNODE;
    }
    float inv = 1.f / l;
    float* op = h + (bs * NNODE + n) * HIDN + hd * 8;
    *(float4*)op       = make_float4(o0*inv, o1*inv, o2*inv, o3*inv);
    *(float4*)(op + 4) = make_float4(o4*inv, o5*inv, o6*inv, o7*inv);
}

// ---------------- temporal attention v4: 4-node chunks, grid 512 -------------
// grid 512 = (b [4]) x (4-node chunk [128]); 384 threads = (sq, nl, hd).
// K/V rows [tt][r=nl*8+hd][9]: 27.6 KB total; bank = (9r) mod 32, gcd(9,32)=1
// -> 2-way free on staging and reads. Same expression order as v3 ->
// bit-identical.
__global__ __launch_bounds__(384, 4) void temporal_attn_kernel(
    const float* __restrict__ q, const float* __restrict__ k, const float* __restrict__ v,
    float* __restrict__ h) {
    __shared__ float Ks2[SS][32][9];   // 13824 B
    __shared__ float Vs2[SS][32][9];   // 13824 B
    int b  = blockIdx.x >> 7;
    int n0 = (blockIdx.x & 127) * 4;
    int t = threadIdx.x;
    // stage: thread t owns (tt = t>>5, r = t&31): one 8-float row of K and V
    {
        int tt = t >> 5, r = t & 31;
        int nl = r >> 3, hd = r & 7;
        long goff = ((long)((b * SS + tt) * NNODE) + n0 + nl) * HIDN + hd * 8;
        float4 k0 = *(const float4*)(k + goff);
        float4 k1 = *(const float4*)(k + goff + 4);
        float4 v0 = *(const float4*)(v + goff);
        float4 v1 = *(const float4*)(v + goff + 4);
        float* kd = &Ks2[tt][r][0];
        float* vd = &Vs2[tt][r][0];
        kd[0]=k0.x; kd[1]=k0.y; kd[2]=k0.z; kd[3]=k0.w;
        kd[4]=k1.x; kd[5]=k1.y; kd[6]=k1.z; kd[7]=k1.w;
        vd[0]=v0.x; vd[1]=v0.y; vd[2]=v0.z; vd[3]=v0.w;
        vd[4]=v1.x; vd[5]=v1.y; vd[6]=v1.z; vd[7]=v1.w;
    }
    __syncthreads();
    int sq = t >> 5, r = t & 31;       // r = nl*8+hd
    int nl = r >> 3, hd = r & 7;
    const float* qp = q + ((long)((b * SS + sq) * NNODE) + n0 + nl) * HIDN + hd * 8;
    float4 qa = *(const float4*)qp;
    float4 qc = *(const float4*)(qp + 4);
    float s[SS];
#pragma unroll
    for (int tt = 0; tt < SS; ++tt) {
        const float* kd = &Ks2[tt][r][0];
        s[tt] = (qa.x * kd[0] + qa.y * kd[1] + qa.z * kd[2] + qa.w * kd[3] +
                 qc.x * kd[4] + qc.y * kd[5] + qc.z * kd[6] + qc.w * kd[7]) * QSCALE;
    }
    float mx = s[0];
#pragma unroll
    for (int tt = 1; tt < SS; ++tt) mx = fmaxf(mx, s[tt]);
    float l = 0.f;
#pragma unroll
    for (int tt = 0; tt < SS; ++tt) { s[tt] = exp2f(s[tt] - mx); l += s[tt]; }
    float a0=0.f,a1=0.f,a2=0.f,a3=0.f,a4=0.f,a5=0.f,a6=0.f,a7=0.f;
#pragma unroll
    for (int tt = 0; tt < SS; ++tt) {
        const float* vd = &Vs2[tt][r][0];
        float e = s[tt];
        a0 += e * vd[0]; a1 += e * vd[1]; a2 += e * vd[2]; a3 += e * vd[3];
        a4 += e * vd[4]; a5 += e * vd[5]; a6 += e * vd[6]; a7 += e * vd[7];
    }
    float inv = 1.f / l;
    float* op = h + ((long)((b * SS + sq) * NNODE) + n0 + nl) * HIDN + hd * 8;
    *(float4*)op       = make_float4(a0 * inv, a1 * inv, a2 * inv, a3 * inv);
    *(float4*)(op + 4) = make_float4(a4 * inv, a5 * inv, a6 * inv, a7 * inv);
}

// ---------------- output projection: h[:, S-1] @ raw WoutT + raw bout --------
__global__ void out_proj_kernel(const float* __restrict__ h, const void* __restrict__ W,
                                const void* __restrict__ b, void* __restrict__ out,
                                const int* __restrict__ flagp) {
    int fl = (*flagp != 0);
    int t = blockIdx.x * blockDim.x + threadIdx.x;
    if (t >= BB * NNODE * 3) return;
    int c  = t % 3;
    int bn = t / 3;
    int n  = bn & (NNODE - 1);
    int bb = bn >> 9;
    const float* hp = h + ((bb * SS + (SS - 1)) * NNODE + n) * HIDN;
    float a = ld(b, c, fl);
#pragma unroll
    for (int i = 0; i < HIDN; i += 4) {
        float4 h4 = *(const float4*)(hp + i);
        a += h4.x * ld(W, c * 64 + i,     fl) + h4.y * ld(W, c * 64 + i + 1, fl)
           + h4.z * ld(W, c * 64 + i + 2, fl) + h4.w * ld(W, c * 64 + i + 3, fl);
    }
    if (fl) ((float*)out)[t] = a;
    else    ((__hip_bfloat16*)out)[t] = __float2bfloat16(a);
}

extern "C" void kernel_launch(void* const* d_in, const int* in_sizes, int n_in,
                              void* d_out, int out_size, void* d_ws, size_t ws_size,
                              hipStream_t stream) {
    const int* ei = (const int*)d_in[1];

    float* ws = (float*)d_ws;
    int*   flag    = (int*)ws;                    // 64 floats reserved
    int*   row_ptr = (int*)(ws + 64);             // 513 ints (reserve 576)
    u16*   col_idx = (u16*)(ws + 640);            // 8192 u16 (4096 float slots)
    float* wTs   = ws + 640 + 4096;               // 2*12288
    float* wTt   = wTs + 24576;                   // 2*12288
    float* bsp   = wTt + 24576;                   // 2*192
    float* btp   = bsp + 384;                     // 2*192
    float* hbuf  = btp + 384;                     // ROWS*64 each
    float* qbuf  = hbuf + ROWS * HIDN;
    float* kbuf  = qbuf + ROWS * HIDN;
    float* vbuf  = kbuf + ROWS * HIDN;

    // dtype from host-visible byte sizes; runtime-detect only if ambiguous
    int flv = -1;
    if (in_sizes) {
        if (in_sizes[0] == XELEMS * 2) flv = 0;        // bf16
        else if (in_sizes[0] == XELEMS * 4) flv = 1;   // fp32
    }
    if (flv >= 0) {
        (void)hipMemsetAsync(flag, flv, sizeof(int), stream);
    } else {
        (void)hipMemsetAsync(flag, 0, sizeof(int), stream);
        detect_kernel<<<64, 256, 0, stream>>>((const u16*)d_in[0], flag);
    }

    PrepArgs pr;
    pr.x = d_in[0]; pr.Win = d_in[2]; pr.bin = d_in[3]; pr.h = hbuf;
    pr.Wq[0] = d_in[4];  pr.bq[0] = d_in[5];
    pr.Wk[0] = d_in[6];  pr.bk[0] = d_in[7];
    pr.Wv[0] = d_in[8];  pr.bv[0] = d_in[9];
    pr.Wq[1] = d_in[10]; pr.bq[1] = d_in[11];
    pr.Wk[1] = d_in[12]; pr.bk[1] = d_in[13];
    pr.Wv[1] = d_in[14]; pr.bv[1] = d_in[15];
    pr.wT[0] = wTs; pr.bp[0] = bsp;
    pr.wT[1] = wTt; pr.bp[1] = btp;
    pr.ei = ei; pr.row_ptr = row_ptr; pr.col_idx = col_idx;
    prep_kernel<<<384 + 96 + 1, 512, 0, stream>>>(pr, flag);

    const int GEMM_BLOCKS = ROWS / 16;                       // 1536
    for (int l = 0; l < NLAY; ++l) {
        // spatial
        qkv_gemm_kernel<<<GEMM_BLOCKS, 256, 0, stream>>>(
            hbuf, wTs + l * 12288, bsp + l * 192, qbuf, kbuf, vbuf, 1);
        spatial_attn_kernel<<<BB * SS * NHEADS * 2, 256, 0, stream>>>(
            qbuf, kbuf, vbuf, row_ptr, col_idx, hbuf);
        // temporal
        qkv_gemm_kernel<<<GEMM_BLOCKS, 256, 0, stream>>>(
            hbuf, wTt + l * 12288, btp + l * 192, qbuf, kbuf, vbuf, 0);
        temporal_attn_kernel<<<BB * (NNODE / 4), 384, 0, stream>>>(
            qbuf, kbuf, vbuf, hbuf);
    }
    out_proj_kernel<<<(BB * NNODE * 3 + 255) / 256, 256, 0, stream>>>(
        hbuf, d_in[16], d_in[17], d_out, flag);
}

// Round 11
// 216.659 us; speedup vs baseline: 1.5341x; 1.0763x over previous
//
#include <hip/hip_runtime.h>
#include <hip/hip_bf16.h>

#define HIDN   64
#define NHEADS 8
#define DHEAD  8
#define NLAY   2
#define BB     4
#define SS     12
#define NNODE  512
#define NEDGE  8192
#define XELEMS (BB * SS * NNODE * 3)      // 73728
#define ROWS   (BB * SS * NNODE)          // 24576
#define QSCALE 0.51006967f                // (1/sqrt(8)) * log2(e): exp(x)=exp2(x*log2e)

typedef unsigned short u16;
typedef unsigned int   u32;
typedef __attribute__((ext_vector_type(4))) float f4;   // indexable float4
typedef __attribute__((ext_vector_type(8))) short s8v;  // 8 bf16 (4 VGPRs)

__device__ __forceinline__ float b2f(u16 u) {
    union { u32 i; float f; } c; c.i = ((u32)u) << 16; return c.f;
}
__device__ __forceinline__ u16 f2b(float f) {   // RNE float->bf16 bits
    union { float f; u32 i; } c; c.f = f;
    u32 r = c.i + 0x7FFFu + ((c.i >> 16) & 1u);
    return (u16)(r >> 16);
}
__device__ __forceinline__ u32 pk2(float a, float b) {
    return (u32)f2b(a) | ((u32)f2b(b) << 16);
}
// decode element i of a raw input tensor (fl=1 -> fp32, fl=0 -> bf16)
__device__ __forceinline__ float ld(const void* p, int i, int fl) {
    return fl ? ((const float*)p)[i] : b2f(((const u16*)p)[i]);
}

// -------- dtype detection FALLBACK (only if in_sizes is ambiguous) -----------
__global__ void detect_kernel(const u16* __restrict__ x, int* __restrict__ flag) {
    int i0 = blockIdx.x * 256 + threadIdx.x;
    int bad = 0;
    for (int i = i0; i < XELEMS; i += 64 * 256) {
        float v = fabsf(b2f(x[i]));
        if (!(v <= 100.f)) bad = 1;   // catches huge AND NaN
    }
    if (bad) atomicOr(flag, 1);       // flag=1 -> inputs are fp32
}

// ---------------- PREP: input_proj(bf16 h) + W pack(bf16) + mask/CSR ---------
// Wb16 layout: [p][l][j 0..191][i 0..63] row-major bf16 -> MFMA B-frag loads
// (8 consecutive k per lane) are 16B contiguous.
struct PrepArgs {
    const void* x; const void* Win; const void* bin; u16* h;
    const void* Wq[2]; const void* bq[2];
    const void* Wk[2]; const void* bk[2];
    const void* Wv[2]; const void* bv[2];
    u16* wb; float* bp[2];
    const int* ei; int* row_ptr; u16* col_idx;
};
__global__ __launch_bounds__(512) void prep_kernel(PrepArgs a, const int* __restrict__ flagp) {
    __shared__ u32 msk[NNODE * 16];   // 32 KB (only used by last block)
    __shared__ int sc[512];
    int fl = (*flagp != 0);
    int bid = blockIdx.x;
    int tid = threadIdx.x;
    if (bid < 384) {
        // ---- input projection: 8 consecutive h elems per thread, bf16 out
        int base = (bid * 512 + tid) * 8;     // row*64 + j0
        int row = base >> 6, j0 = base & 63;
        float x0 = ld(a.x, row * 3, fl);
        float x1 = ld(a.x, row * 3 + 1, fl);
        float x2 = ld(a.x, row * 3 + 2, fl);
        float o[8];
#pragma unroll
        for (int jj = 0; jj < 8; ++jj) {
            int j = j0 + jj;
            o[jj] = ld(a.bin, j, fl) + x0 * ld(a.Win, j * 3, fl)
                  + x1 * ld(a.Win, j * 3 + 1, fl) + x2 * ld(a.Win, j * 3 + 2, fl);
        }
        *(uint4*)&a.h[base] = make_uint4(pk2(o[0], o[1]), pk2(o[2], o[3]),
                                         pk2(o[4], o[5]), pk2(o[6], o[7]));
        return;
    }
    if (bid < 480) {
        // ---- weight pack to bf16: dest p*24576 + l*12288 + j*64 + i
        int u = (bid - 384) * 512 + tid;  // 0..49151
        int p = u / 24576;
        int rem = u - p * 24576;
        int l = rem / 12288;
        int t = rem - l * 12288;
        int j = t >> 6, i = t & 63;
        int cg = j >> 6, cc = j & 63;
        const void* W = (cg == 0) ? a.Wq[p] : (cg == 1) ? a.Wk[p] : a.Wv[p];
        a.wb[u] = f2b(ld(W, l * 4096 + cc * 64 + i, fl));
        // ---- bias (fp32): first 768 u's cover 2p x 2l x 192
        if (u < 768) {
            int p2 = u / 384;
            int r3 = u - p2 * 384;
            int l2 = r3 / 192;
            int j2 = r3 - l2 * 192;
            int cg2 = j2 >> 6;
            const void* B = (cg2 == 0) ? a.bq[p2] : (cg2 == 1) ? a.bk[p2] : a.bv[p2];
            a.bp[p2][l2 * 192 + j2] = ld(B, l2 * 64 + (j2 & 63), fl);
        }
        return;
    }
    // ---- mask bitset (LDS) + CSR build, one 512-thread block
    for (int i = tid; i < NNODE * 16; i += 512) msk[i] = 0;
    __syncthreads();
    for (int e = tid; e < NEDGE; e += 512) {
        int r = a.ei[e];           // query row
        int m = a.ei[NEDGE + e];   // key col
        atomicOr(&msk[r * 16 + (m >> 5)], 1u << (m & 31));
    }
    __syncthreads();
    int n = tid;   // 0..511
    u32 w[16];
    int d = 0;
#pragma unroll
    for (int i = 0; i < 16; ++i) { w[i] = msk[n * 16 + i]; d += __popc(w[i]); }
    sc[n] = d;
    __syncthreads();
    for (int s = 1; s < 512; s <<= 1) {
        int v = (n >= s) ? sc[n - s] : 0;
        __syncthreads();
        sc[n] += v;
        __syncthreads();
    }
    int excl = sc[n] - d;
    a.row_ptr[n] = excl;
    if (n == 511) a.row_ptr[512] = sc[511];
    int base = excl;
#pragma unroll
    for (int i = 0; i < 16; ++i) {
        u32 m = w[i];
        while (m) {
            int b = __ffs(m) - 1;
            m &= m - 1;
            a.col_idx[base++] = (u16)(i * 32 + b);
        }
    }
}

// ---------------- q/k/v GEMM v7: MFMA bf16, LDS-transpose epilogue -----------
// Block = 32 rows x 192 cols, 256 thr (4 waves). Wave (rowhalf = w&1,
// colgroup = w>>1 -> 96 cols = 6 tiles). Per wave: 2 A-frags (h rows, bf16) +
// 12 B-frags (W cols) loaded up-front (14-deep MLP), 12 MFMA into fp32 acc.
// C/D (col=lane&15, row=(lane>>4)*4+reg, m89-verified) -> LDS[32][194]
// (stride 194: kg-offset 8 banks -> 2-way free) -> proven R8 coalesced stores.
// Both operands pack k identically (kg*8+32*kh consecutive) so the contraction
// is exact over all 64 k regardless of internal k-ordering.
__global__ __launch_bounds__(256) void qkv_gemm_kernel(
    const u16* __restrict__ hb, const u16* __restrict__ wb,
    const float* __restrict__ bias,
    float* __restrict__ q, float* __restrict__ k, float* __restrict__ v,
    int spatial_layout) {
    __shared__ float Cs[32][194];   // 24.25 KB
    int t = threadIdx.x;
    int row0 = blockIdx.x * 32;
    int lane = t & 63, wv = t >> 6;
    int rowhalf = wv & 1, cg = wv >> 1;      // cg 0..1 -> col base cg*96
    int lrow = lane & 15, kg = lane >> 4;    // kg 0..3 -> k base kg*8
    // A fragments: h rows (bf16), 8 consecutive k per lane
    const u16* hp = hb + (row0 + rowhalf * 16 + lrow) * 64 + kg * 8;
    s8v a0 = *(const s8v*)hp;
    s8v a1 = *(const s8v*)(hp + 32);
    f4 acc[6];
#pragma unroll
    for (int ct = 0; ct < 6; ++ct) acc[ct] = (f4){0.f, 0.f, 0.f, 0.f};
#pragma unroll
    for (int ct = 0; ct < 6; ++ct) {
        const u16* wp = wb + (cg * 96 + ct * 16 + lrow) * 64 + kg * 8;
        s8v b0 = *(const s8v*)wp;
        s8v b1 = *(const s8v*)(wp + 32);
        acc[ct] = __builtin_amdgcn_mfma_f32_16x16x32_bf16(a0, b0, acc[ct], 0, 0, 0);
        acc[ct] = __builtin_amdgcn_mfma_f32_16x16x32_bf16(a1, b1, acc[ct], 0, 0, 0);
    }
    // transpose through LDS
#pragma unroll
    for (int ct = 0; ct < 6; ++ct)
#pragma unroll
        for (int r = 0; r < 4; ++r)
            Cs[rowhalf * 16 + kg * 4 + r][cg * 96 + ct * 16 + lrow] = acc[ct][r];
    __syncthreads();
    // readout + bias + coalesced stores (R8-proven pattern)
    int c = t & 63, w2 = t >> 6;
    int rowoff = w2 * 8;
    float bb0 = bias[c], bb1 = bias[64 + c], bb2 = bias[128 + c];
    if (spatial_layout) {
        int bs = row0 >> 9, n0 = row0 & 511;
        int hd = c >> 3, dh = c & 7;
        long off = ((long)(bs * 8 + hd) * 512 + n0 + rowoff) * 8 + dh;
        float* qp = q + off;
        float* kp = k + off;
        float* vp = v + off;
#pragma unroll
        for (int rr = 0; rr < 8; ++rr) {
            qp[rr * 8] = (Cs[rowoff + rr][c] + bb0) * QSCALE;
            kp[rr * 8] = Cs[rowoff + rr][64 + c] + bb1;
            vp[rr * 8] = Cs[rowoff + rr][128 + c] + bb2;
        }
    } else {
        int off = (row0 + rowoff) * 64 + c;
        float* qp = q + off;
        float* kp = k + off;
        float* vp = v + off;
#pragma unroll
        for (int rr = 0; rr < 8; ++rr) {
            qp[rr * 64] = Cs[rowoff + rr][c] + bb0;
            kp[rr * 64] = Cs[rowoff + rr][64 + c] + bb1;
            vp[rr * 64] = Cs[rowoff + rr][128 + c] + bb2;
        }
    }
}

// ---------------- spatial attention: SPARSE (avg degree 16/512) --------------
// q/k/v fp32 head-major (unchanged); h OUT is bf16 now.
__global__ __launch_bounds__(256) void spatial_attn_kernel(
    const float* __restrict__ qh, const float* __restrict__ kh, const float* __restrict__ vh,
    const int* __restrict__ row_ptr, const u16* __restrict__ col_idx,
    u16* __restrict__ h) {
    __shared__ __align__(16) float Ks[NNODE][8];   // 16 KB
    __shared__ __align__(16) float Vs[NNODE][8];   // 16 KB
    int bxx = blockIdx.x;
    int pair = bxx >> 1, halfq = bxx & 1;
    int bs = pair >> 3, hd = pair & 7;      // bs = b*S+s in [0,48)
    const float* kp = kh + pair * (NNODE * 8);
    const float* vp = vh + pair * (NNODE * 8);
    int t = threadIdx.x;
#pragma unroll
    for (int i = 0; i < 2; ++i) {
        int r = t + 256 * i;
        float4 k0 = *(const float4*)(kp + r * 8);
        float4 k1 = *(const float4*)(kp + r * 8 + 4);
        float4 v0 = *(const float4*)(vp + r * 8);
        float4 v1 = *(const float4*)(vp + r * 8 + 4);
        *(float4*)&Ks[r][0] = k0; *(float4*)&Ks[r][4] = k1;
        *(float4*)&Vs[r][0] = v0; *(float4*)&Vs[r][4] = v1;
    }
    __syncthreads();
    int n = halfq * 256 + t;
    const float* qp = qh + (pair * NNODE + n) * 8;
    float4 qa = *(const float4*)qp;
    float4 qc = *(const float4*)(qp + 4);
    int e0 = row_ptr[n], e1 = row_ptr[n + 1];
    float l = 0.f;
    float o0=0.f,o1=0.f,o2=0.f,o3=0.f,o4=0.f,o5=0.f,o6=0.f,o7=0.f;
    for (int e = e0; e < e1; ++e) {
        int m = col_idx[e];
        float4 ka = *(const float4*)&Ks[m][0];
        float4 kc = *(const float4*)&Ks[m][4];
        float s = qa.x*ka.x + qa.y*ka.y + qa.z*ka.z + qa.w*ka.w
                + qc.x*kc.x + qc.y*kc.y + qc.z*kc.z + qc.w*kc.w;
        float p = exp2f(s);          // q prescaled by (1/sqrt8)*log2e
        l += p;
        float4 va = *(const float4*)&Vs[m][0];
        float4 vc = *(const float4*)&Vs[m][4];
        o0 += p*va.x; o1 += p*va.y; o2 += p*va.z; o3 += p*va.w;
        o4 += p*vc.x; o5 += p*vc.y; o6 += p*vc.z; o7 += p*vc.w;
    }
    if (e1 == e0) {                  // fully-masked row: uniform mean(V)
        for (int m = 0; m < NNODE; ++m) {
            o0 += Vs[m][0]; o1 += Vs[m][1]; o2 += Vs[m][2]; o3 += Vs[m][3];
            o4 += Vs[m][4]; o5 += Vs[m][5]; o6 += Vs[m][6]; o7 += Vs[m][7];
        }
        l = (float)NNODE;
    }
    float inv = 1.f / l;
    u16* op = h + ((long)(bs * NNODE + n)) * HIDN + hd * 8;
    *(uint4*)op = make_uint4(pk2(o0*inv, o1*inv), pk2(o2*inv, o3*inv),
                             pk2(o4*inv, o5*inv), pk2(o6*inv, o7*inv));
}

// ---------------- temporal attention v4: 4-node chunks, grid 512 -------------
// q/k/v fp32 (unchanged); h OUT is bf16 now.
__global__ __launch_bounds__(384, 4) void temporal_attn_kernel(
    const float* __restrict__ q, const float* __restrict__ k, const float* __restrict__ v,
    u16* __restrict__ h) {
    __shared__ float Ks2[SS][32][9];   // 13824 B
    __shared__ float Vs2[SS][32][9];   // 13824 B
    int b  = blockIdx.x >> 7;
    int n0 = (blockIdx.x & 127) * 4;
    int t = threadIdx.x;
    {
        int tt = t >> 5, r = t & 31;
        int nl = r >> 3, hd = r & 7;
        long goff = ((long)((b * SS + tt) * NNODE) + n0 + nl) * HIDN + hd * 8;
        float4 k0 = *(const float4*)(k + goff);
        float4 k1 = *(const float4*)(k + goff + 4);
        float4 v0 = *(const float4*)(v + goff);
        float4 v1 = *(const float4*)(v + goff + 4);
        float* kd = &Ks2[tt][r][0];
        float* vd = &Vs2[tt][r][0];
        kd[0]=k0.x; kd[1]=k0.y; kd[2]=k0.z; kd[3]=k0.w;
        kd[4]=k1.x; kd[5]=k1.y; kd[6]=k1.z; kd[7]=k1.w;
        vd[0]=v0.x; vd[1]=v0.y; vd[2]=v0.z; vd[3]=v0.w;
        vd[4]=v1.x; vd[5]=v1.y; vd[6]=v1.z; vd[7]=v1.w;
    }
    __syncthreads();
    int sq = t >> 5, r = t & 31;       // r = nl*8+hd
    int nl = r >> 3, hd = r & 7;
    const float* qp = q + ((long)((b * SS + sq) * NNODE) + n0 + nl) * HIDN + hd * 8;
    float4 qa = *(const float4*)qp;
    float4 qc = *(const float4*)(qp + 4);
    float s[SS];
#pragma unroll
    for (int tt = 0; tt < SS; ++tt) {
        const float* kd = &Ks2[tt][r][0];
        s[tt] = (qa.x * kd[0] + qa.y * kd[1] + qa.z * kd[2] + qa.w * kd[3] +
                 qc.x * kd[4] + qc.y * kd[5] + qc.z * kd[6] + qc.w * kd[7]) * QSCALE;
    }
    float mx = s[0];
#pragma unroll
    for (int tt = 1; tt < SS; ++tt) mx = fmaxf(mx, s[tt]);
    float l = 0.f;
#pragma unroll
    for (int tt = 0; tt < SS; ++tt) { s[tt] = exp2f(s[tt] - mx); l += s[tt]; }
    float a0=0.f,a1=0.f,a2=0.f,a3=0.f,a4=0.f,a5=0.f,a6=0.f,a7=0.f;
#pragma unroll
    for (int tt = 0; tt < SS; ++tt) {
        const float* vd = &Vs2[tt][r][0];
        float e = s[tt];
        a0 += e * vd[0]; a1 += e * vd[1]; a2 += e * vd[2]; a3 += e * vd[3];
        a4 += e * vd[4]; a5 += e * vd[5]; a6 += e * vd[6]; a7 += e * vd[7];
    }
    float inv = 1.f / l;
    u16* op = h + ((long)((b * SS + sq) * NNODE) + n0 + nl) * HIDN + hd * 8;
    *(uint4*)op = make_uint4(pk2(a0*inv, a1*inv), pk2(a2*inv, a3*inv),
                             pk2(a4*inv, a5*inv), pk2(a6*inv, a7*inv));
}

// ---------------- output projection: bf16 h[:, S-1] @ raw WoutT + raw bout ---
__global__ void out_proj_kernel(const u16* __restrict__ h, const void* __restrict__ W,
                                const void* __restrict__ b, void* __restrict__ out,
                                const int* __restrict__ flagp) {
    int fl = (*flagp != 0);
    int t = blockIdx.x * blockDim.x + threadIdx.x;
    if (t >= BB * NNODE * 3) return;
    int c  = t % 3;
    int bn = t / 3;
    int n  = bn & (NNODE - 1);
    int bb = bn >> 9;
    const u16* hp = h + ((long)((bb * SS + (SS - 1)) * NNODE + n)) * HIDN;
    float a = ld(b, c, fl);
#pragma unroll
    for (int i = 0; i < HIDN; i += 8) {
        uint4 hv = *(const uint4*)&hp[i];
        const u32 hw[4] = {hv.x, hv.y, hv.z, hv.w};
#pragma unroll
        for (int j2 = 0; j2 < 4; ++j2) {
            float hlo = b2f((u16)(hw[j2] & 0xFFFF));
            float hhi = b2f((u16)(hw[j2] >> 16));
            a += hlo * ld(W, c * 64 + i + j2 * 2,     fl)
               + hhi * ld(W, c * 64 + i + j2 * 2 + 1, fl);
        }
    }
    if (fl) ((float*)out)[t] = a;
    else    ((__hip_bfloat16*)out)[t] = __float2bfloat16(a);
}

extern "C" void kernel_launch(void* const* d_in, const int* in_sizes, int n_in,
                              void* d_out, int out_size, void* d_ws, size_t ws_size,
                              hipStream_t stream) {
    const int* ei = (const int*)d_in[1];

    float* ws = (float*)d_ws;
    int*   flag    = (int*)ws;                    // 64 floats reserved
    int*   row_ptr = (int*)(ws + 64);             // 513 ints (reserve 576)
    u16*   col_idx = (u16*)(ws + 640);            // 8192 u16 (4096 float slots)
    u16*   wb16  = (u16*)(ws + 4736);             // 49152 u16 = 24576 float slots
    float* bsp   = ws + 4736 + 24576;             // 2*192
    float* btp   = bsp + 384;                     // 2*192
    u16*   hb16  = (u16*)(btp + 384);             // ROWS*64 u16 = 786432 floats
    float* qbuf  = (float*)(btp + 384 + 786432);
    float* kbuf  = qbuf + ROWS * HIDN;
    float* vbuf  = kbuf + ROWS * HIDN;

    // dtype from host-visible byte sizes; runtime-detect only if ambiguous
    int flv = -1;
    if (in_sizes) {
        if (in_sizes[0] == XELEMS * 2) flv = 0;        // bf16
        else if (in_sizes[0] == XELEMS * 4) flv = 1;   // fp32
    }
    if (flv >= 0) {
        (void)hipMemsetAsync(flag, flv, sizeof(int), stream);
    } else {
        (void)hipMemsetAsync(flag, 0, sizeof(int), stream);
        detect_kernel<<<64, 256, 0, stream>>>((const u16*)d_in[0], flag);
    }

    PrepArgs pr;
    pr.x = d_in[0]; pr.Win = d_in[2]; pr.bin = d_in[3]; pr.h = hb16;
    pr.Wq[0] = d_in[4];  pr.bq[0] = d_in[5];
    pr.Wk[0] = d_in[6];  pr.bk[0] = d_in[7];
    pr.Wv[0] = d_in[8];  pr.bv[0] = d_in[9];
    pr.Wq[1] = d_in[10]; pr.bq[1] = d_in[11];
    pr.Wk[1] = d_in[12]; pr.bk[1] = d_in[13];
    pr.Wv[1] = d_in[14]; pr.bv[1] = d_in[15];
    pr.wb = wb16; pr.bp[0] = bsp; pr.bp[1] = btp;
    pr.ei = ei; pr.row_ptr = row_ptr; pr.col_idx = col_idx;
    prep_kernel<<<384 + 96 + 1, 512, 0, stream>>>(pr, flag);

    const int GEMM_BLOCKS = ROWS / 32;                       // 768
    for (int l = 0; l < NLAY; ++l) {
        // spatial: Wb16 slice p=0
        qkv_gemm_kernel<<<GEMM_BLOCKS, 256, 0, stream>>>(
            hb16, wb16 + l * 12288, bsp + l * 192, qbuf, kbuf, vbuf, 1);
        spatial_attn_kernel<<<BB * SS * NHEADS * 2, 256, 0, stream>>>(
            qbuf, kbuf, vbuf, row_ptr, col_idx, hb16);
        // temporal: Wb16 slice p=1
        qkv_gemm_kernel<<<GEMM_BLOCKS, 256, 0, stream>>>(
            hb16, wb16 + 24576 + l * 12288, btp + l * 192, qbuf, kbuf, vbuf, 0);
        temporal_attn_kernel<<<BB * (NNODE / 4), 384, 0, stream>>>(
            qbuf, kbuf, vbuf, hb16);
    }
    out_proj_kernel<<<(BB * NNODE * 3 + 255) / 256, 256, 0, stream>>>(
        hb16, d_in[16], d_in[17], d_out, flag);
}

// Round 13
// 183.142 us; speedup vs baseline: 1.8148x; 1.1830x over previous
//
#include <hip/hip_runtime.h>
#include <hip/hip_bf16.h>

#define HIDN   64
#define NHEADS 8
#define DHEAD  8
#define NLAY   2
#define BB     4
#define SS     12
#define NNODE  512
#define NEDGE  8192
#define XELEMS (BB * SS * NNODE * 3)      // 73728
#define ROWS   (BB * SS * NNODE)          // 24576
#define QSCALE 0.51006967f                // (1/sqrt(8)) * log2(e): exp(x)=exp2(x*log2e)

typedef unsigned short u16;
typedef unsigned int   u32;
typedef __attribute__((ext_vector_type(4))) float f4;   // indexable float4
typedef __attribute__((ext_vector_type(8))) short s8v;  // 8 bf16 (4 VGPRs)

__device__ __forceinline__ float b2f(u16 u) {
    union { u32 i; float f; } c; c.i = ((u32)u) << 16; return c.f;
}
__device__ __forceinline__ u16 f2b(float f) {   // RNE float->bf16 bits
    union { float f; u32 i; } c; c.f = f;
    u32 r = c.i + 0x7FFFu + ((c.i >> 16) & 1u);
    return (u16)(r >> 16);
}
__device__ __forceinline__ u32 pk2(float a, float b) {
    return (u32)f2b(a) | ((u32)f2b(b) << 16);
}
// decode element i of a raw input tensor (fl=1 -> fp32, fl=0 -> bf16)
__device__ __forceinline__ float ld(const void* p, int i, int fl) {
    return fl ? ((const float*)p)[i] : b2f(((const u16*)p)[i]);
}

// -------- dtype detection FALLBACK (only if in_sizes is ambiguous) -----------
__global__ void detect_kernel(const u16* __restrict__ x, int* __restrict__ flag) {
    int i0 = blockIdx.x * 256 + threadIdx.x;
    int bad = 0;
    for (int i = i0; i < XELEMS; i += 64 * 256) {
        float v = fabsf(b2f(x[i]));
        if (!(v <= 100.f)) bad = 1;   // catches huge AND NaN
    }
    if (bad) atomicOr(flag, 1);       // flag=1 -> inputs are fp32
}

// ---------------- PREP: input_proj(bf16) + W packs(bf16) + mask/CSR ----------
// wb (temporal): [l][j 0..191][i 0..63] bf16 (B-frag loads 16B contiguous).
// whd (spatial, per-head): [l][hd][tile2][c 0..15][i 0..63] bf16;
//   tile0 cols = [Wk col hd*8+c | Wv col hd*8+(c-8)], tile1 = [Wq | zeros].
struct PrepArgs {
    const void* x; const void* Win; const void* bin; u16* h;
    const void* Wq[2]; const void* bq[2];
    const void* Wk[2]; const void* bk[2];
    const void* Wv[2]; const void* bv[2];
    u16* wb; u16* whd; float* bp[2];
    const int* ei; int* row_ptr; u16* col_idx;
};
__global__ __launch_bounds__(512) void prep_kernel(PrepArgs a, const int* __restrict__ flagp) {
    __shared__ u32 msk[NNODE * 16];   // 32 KB (only used by last block)
    __shared__ int sc[512];
    int fl = (*flagp != 0);
    int bid = blockIdx.x;
    int tid = threadIdx.x;
    if (bid < 384) {
        // ---- input projection: 8 consecutive h elems per thread, bf16 out
        int base = (bid * 512 + tid) * 8;     // row*64 + j0
        int row = base >> 6, j0 = base & 63;
        float x0 = ld(a.x, row * 3, fl);
        float x1 = ld(a.x, row * 3 + 1, fl);
        float x2 = ld(a.x, row * 3 + 2, fl);
        float o[8];
#pragma unroll
        for (int jj = 0; jj < 8; ++jj) {
            int j = j0 + jj;
            o[jj] = ld(a.bin, j, fl) + x0 * ld(a.Win, j * 3, fl)
                  + x1 * ld(a.Win, j * 3 + 1, fl) + x2 * ld(a.Win, j * 3 + 2, fl);
        }
        *(uint4*)&a.h[base] = make_uint4(pk2(o[0], o[1]), pk2(o[2], o[3]),
                                         pk2(o[4], o[5]), pk2(o[6], o[7]));
        return;
    }
    if (bid < 432) {
        // ---- temporal W full pack (p=1): dest l*12288 + j*64 + i
        int u = (bid - 384) * 512 + tid;  // 0..24575
        int l = u / 12288;
        int t = u - l * 12288;
        int j = t >> 6, i = t & 63;
        int cg = j >> 6, cc = j & 63;
        const void* W = (cg == 0) ? a.Wq[1] : (cg == 1) ? a.Wk[1] : a.Wv[1];
        a.wb[u] = f2b(ld(W, l * 4096 + cc * 64 + i, fl));
        // ---- bias (both p): first 768 u's cover 2p x 2l x 192
        if (u < 768) {
            int p2 = u / 384;
            int r3 = u - p2 * 384;
            int l2 = r3 / 192;
            int j2 = r3 - l2 * 192;
            int cg2 = j2 >> 6;
            const void* B = (cg2 == 0) ? a.bq[p2] : (cg2 == 1) ? a.bk[p2] : a.bv[p2];
            a.bp[p2][l2 * 192 + j2] = ld(B, l2 * 64 + (j2 & 63), fl);
        }
        return;
    }
    if (bid < 496) {
        // ---- spatial per-head pack: u -> [l][hd][tile][c][i]
        int u = (bid - 432) * 512 + tid;  // 0..32767
        int l    = u >> 14;
        int rem  = u & 16383;
        int hd   = rem >> 11;
        int rem2 = rem & 2047;
        int tile = rem2 >> 10;
        int rem3 = rem2 & 1023;
        int c    = rem3 >> 6;
        int i    = rem3 & 63;
        int j;
        if (tile == 0) j = (c < 8) ? (64 + hd * 8 + c) : (128 + hd * 8 + (c - 8));
        else           j = (c < 8) ? (hd * 8 + c) : -1;
        u16 val = 0;
        if (j >= 0) {
            int cg = j >> 6, cc = j & 63;
            const void* W = (cg == 0) ? a.Wq[0] : (cg == 1) ? a.Wk[0] : a.Wv[0];
            val = f2b(ld(W, l * 4096 + cc * 64 + i, fl));
        }
        a.whd[u] = val;
        return;
    }
    // ---- mask bitset (LDS) + CSR build, one 512-thread block
    for (int i = tid; i < NNODE * 16; i += 512) msk[i] = 0;
    __syncthreads();
    for (int e = tid; e < NEDGE; e += 512) {
        int r = a.ei[e];           // query row
        int m = a.ei[NEDGE + e];   // key col
        atomicOr(&msk[r * 16 + (m >> 5)], 1u << (m & 31));
    }
    __syncthreads();
    int n = tid;   // 0..511
    u32 w[16];
    int d = 0;
#pragma unroll
    for (int i = 0; i < 16; ++i) { w[i] = msk[n * 16 + i]; d += __popc(w[i]); }
    sc[n] = d;
    __syncthreads();
    for (int s = 1; s < 512; s <<= 1) {
        int v = (n >= s) ? sc[n - s] : 0;
        __syncthreads();
        sc[n] += v;
        __syncthreads();
    }
    int excl = sc[n] - d;
    a.row_ptr[n] = excl;
    if (n == 511) a.row_ptr[512] = sc[511];
    int base = excl;
#pragma unroll
    for (int i = 0; i < 16; ++i) {
        u32 m = w[i];
        while (m) {
            int b = __ffs(m) - 1;
            m &= m - 1;
            a.col_idx[base++] = (u16)(i * 32 + b);
        }
    }
}

// ---------------- FUSED spatial: MFMA qkv (head slice) + sparse attention ----
// grid 768 = (pair, half); 256 thr (4 waves). Per wave: 8 K/V row-tiles x2
// MFMA + 4 q row-tiles x2 MFMA (single [k8|v8] / [q8|0] B-frag pair, held in
// regs). C (m89: row=(lane>>4)*4+reg, col=lane&15 -- R11-HW-proven) written
// straight to Ks/Vs/qS LDS. ONE barrier, then R8 sparse-CSR attention.
// Same MFMA+bias order as R11 -> q/k/v values bit-identical to R11.
__global__ __launch_bounds__(256) void spat_fused_kernel(
    const u16* __restrict__ hb, const u16* __restrict__ whd,
    const float* __restrict__ bp,
    const int* __restrict__ row_ptr, const u16* __restrict__ col_idx,
    u16* __restrict__ h2) {
    __shared__ __align__(16) float Ks[NNODE][8];   // 16 KB
    __shared__ __align__(16) float Vs[NNODE][8];   // 16 KB
    __shared__ float qS[256][9];                   //  9 KB
    int bxx = blockIdx.x;
    int pair = bxx >> 1, half = bxx & 1;
    int bs = pair >> 3, hd = pair & 7;      // bs = b*S+s in [0,48)
    int t = threadIdx.x;
    int lane = t & 63, wv = t >> 6;
    int lrow = lane & 15, kg = lane >> 4;
    const u16* hsl = hb + (long)bs * NNODE * HIDN;
    const u16* wkv = whd + hd * 2048;            // tile0: [k8|v8]
    const u16* wq  = whd + hd * 2048 + 1024;     // tile1: [q8|0]
    s8v bkv0 = *(const s8v*)(wkv + lrow * 64 + kg * 8);
    s8v bkv1 = *(const s8v*)(wkv + lrow * 64 + kg * 8 + 32);
    s8v bq0  = *(const s8v*)(wq  + lrow * 64 + kg * 8);
    s8v bq1  = *(const s8v*)(wq  + lrow * 64 + kg * 8 + 32);
    float biasKV = (lrow < 8) ? bp[64 + hd * 8 + lrow] : bp[128 + hd * 8 + (lrow & 7)];
    float biasQ  = bp[hd * 8 + (lrow & 7)];
    // K/V GEMM: 8 row-tiles per wave (covers all 512 nodes)
#pragma unroll
    for (int s = 0; s < 8; ++s) {
        int rt = wv * 8 + s;                 // 0..31
        const u16* ap = hsl + (rt * 16 + lrow) * 64 + kg * 8;
        s8v ha0 = *(const s8v*)ap;
        s8v ha1 = *(const s8v*)(ap + 32);
        f4 acc = (f4){0.f, 0.f, 0.f, 0.f};
        acc = __builtin_amdgcn_mfma_f32_16x16x32_bf16(ha0, bkv0, acc, 0, 0, 0);
        acc = __builtin_amdgcn_mfma_f32_16x16x32_bf16(ha1, bkv1, acc, 0, 0, 0);
        int node = rt * 16 + kg * 4;
        if (lrow < 8) {
#pragma unroll
            for (int r = 0; r < 4; ++r) Ks[node + r][lrow] = acc[r] + biasKV;
        } else {
#pragma unroll
            for (int r = 0; r < 4; ++r) Vs[node + r][lrow & 7] = acc[r] + biasKV;
        }
    }
    // q GEMM: 4 row-tiles per wave (covers this half's 256 rows)
#pragma unroll
    for (int s = 0; s < 4; ++s) {
        int rtq = wv * 4 + s;                // 0..15
        const u16* ap = hsl + (half * 256 + rtq * 16 + lrow) * 64 + kg * 8;
        s8v ha0 = *(const s8v*)ap;
        s8v ha1 = *(const s8v*)(ap + 32);
        f4 acc = (f4){0.f, 0.f, 0.f, 0.f};
        acc = __builtin_amdgcn_mfma_f32_16x16x32_bf16(ha0, bq0, acc, 0, 0, 0);
        acc = __builtin_amdgcn_mfma_f32_16x16x32_bf16(ha1, bq1, acc, 0, 0, 0);
        if (lrow < 8) {
            int nl = rtq * 16 + kg * 4;
#pragma unroll
            for (int r = 0; r < 4; ++r) qS[nl + r][lrow] = (acc[r] + biasQ) * QSCALE;
        }
    }
    __syncthreads();
    // ---- sparse attention (R8-proven) ----
    int n = half * 256 + t;
    float4 qa = make_float4(qS[t][0], qS[t][1], qS[t][2], qS[t][3]);
    float4 qc = make_float4(qS[t][4], qS[t][5], qS[t][6], qS[t][7]);
    int e0 = row_ptr[n], e1 = row_ptr[n + 1];
    float l = 0.f;
    float o0=0.f,o1=0.f,o2=0.f,o3=0.f,o4=0.f,o5=0.f,o6=0.f,o7=0.f;
    for (int e = e0; e < e1; ++e) {
        int m = col_idx[e];
        float4 ka = *(const float4*)&Ks[m][0];
        float4 kc = *(const float4*)&Ks[m][4];
        float s = qa.x*ka.x + qa.y*ka.y + qa.z*ka.z + qa.w*ka.w
                + qc.x*kc.x + qc.y*kc.y + qc.z*kc.z + qc.w*kc.w;
        float p = exp2f(s);          // q prescaled by (1/sqrt8)*log2e
        l += p;
        float4 va = *(const float4*)&Vs[m][0];
        float4 vc = *(const float4*)&Vs[m][4];
        o0 += p*va.x; o1 += p*va.y; o2 += p*va.z; o3 += p*va.w;
        o4 += p*vc.x; o5 += p*vc.y; o6 += p*vc.z; o7 += p*vc.w;
    }
    if (e1 == e0) {                  // fully-masked row: uniform mean(V)
        for (int m = 0; m < NNODE; ++m) {
            o0 += Vs[m][0]; o1 += Vs[m][1]; o2 += Vs[m][2]; o3 += Vs[m][3];
            o4 += Vs[m][4]; o5 += Vs[m][5]; o6 += Vs[m][6]; o7 += Vs[m][7];
        }
        l = (float)NNODE;
    }
    float inv = 1.f / l;
    u16* op = h2 + ((long)(bs * NNODE + n)) * HIDN + hd * 8;
    *(uint4*)op = make_uint4(pk2(o0*inv, o1*inv), pk2(o2*inv, o3*inv),
                             pk2(o4*inv, o5*inv), pk2(o6*inv, o7*inv));
}

// ---------------- FUSED temporal: MFMA qkv (48x192, no redundancy) + attn ----
// grid 512 = (b, 4-node chunk); 384 thr (6 waves). Wave (rt = wv>>1,
// ct0 = (wv&1)*6): A-frags loaded once, 6 col-tiles x2 MFMA = 12 MFMAs.
// C -> S[3][12][32][9] (stride-9 conflict-free). ONE barrier, then R8-v4
// temporal attention. Same MFMA+bias order as R11 -> bit-identical values.
__global__ __launch_bounds__(384) void temp_fused_kernel(
    const u16* __restrict__ h2b, const u16* __restrict__ wb,
    const float* __restrict__ bp, u16* __restrict__ h) {
    __shared__ float S[3][SS][32][9];   // 41472 B
    int b  = blockIdx.x >> 7;
    int n0 = (blockIdx.x & 127) * 4;
    int t = threadIdx.x;
    int lane = t & 63, wv = t >> 6;     // 6 waves
    int lrow = lane & 15, kg = lane >> 4;
    int rt  = wv >> 1;                  // 0..2
    int ct0 = (wv & 1) * 6;
    // A-frags: row gr = rt*16 + lrow -> (tt = gr>>2, nl = gr&3)
    int gr = rt * 16 + lrow;
    int tta = gr >> 2, nla = gr & 3;
    const u16* ap = h2b + ((long)((b * SS + tta) * NNODE) + n0 + nla) * HIDN + kg * 8;
    s8v haf0 = *(const s8v*)ap;
    s8v haf1 = *(const s8v*)(ap + 32);
#pragma unroll
    for (int s = 0; s < 6; ++s) {
        int ct = ct0 + s;
        const u16* wp = wb + (ct * 16 + lrow) * 64 + kg * 8;
        s8v wb0 = *(const s8v*)wp;
        s8v wb1 = *(const s8v*)(wp + 32);
        f4 acc = (f4){0.f, 0.f, 0.f, 0.f};
        acc = __builtin_amdgcn_mfma_f32_16x16x32_bf16(haf0, wb0, acc, 0, 0, 0);
        acc = __builtin_amdgcn_mfma_f32_16x16x32_bf16(haf1, wb1, acc, 0, 0, 0);
        int j = ct * 16 + lrow;
        float bb = bp[j];
        int tz = j >> 6, cc = j & 63, hd2 = cc >> 3, dh = cc & 7;
#pragma unroll
        for (int r = 0; r < 4; ++r) {
            int gr2 = rt * 16 + kg * 4 + r;
            S[tz][gr2 >> 2][(gr2 & 3) * 8 + hd2][dh] = acc[r] + bb;
        }
    }
    __syncthreads();
    // ---- temporal attention (R8-v4-proven) ----
    int sq = t >> 5, r = t & 31;        // r = nl*8+hd
    int nl = r >> 3, hd = r & 7;
    const float* qd = &S[0][sq][r][0];
    float q0=qd[0],q1=qd[1],q2=qd[2],q3=qd[3],q4=qd[4],q5=qd[5],q6=qd[6],q7=qd[7];
    float s[SS];
#pragma unroll
    for (int tt = 0; tt < SS; ++tt) {
        const float* kd = &S[1][tt][r][0];
        s[tt] = (q0 * kd[0] + q1 * kd[1] + q2 * kd[2] + q3 * kd[3] +
                 q4 * kd[4] + q5 * kd[5] + q6 * kd[6] + q7 * kd[7]) * QSCALE;
    }
    float mx = s[0];
#pragma unroll
    for (int tt = 1; tt < SS; ++tt) mx = fmaxf(mx, s[tt]);
    float l = 0.f;
#pragma unroll
    for (int tt = 0; tt < SS; ++tt) { s[tt] = exp2f(s[tt] - mx); l += s[tt]; }
    float a0=0.f,a1=0.f,a2=0.f,a3=0.f,a4=0.f,a5=0.f,a6=0.f,a7=0.f;
#pragma unroll
    for (int tt = 0; tt < SS; ++tt) {
        const float* vd = &S[2][tt][r][0];
        float e = s[tt];
        a0 += e * vd[0]; a1 += e * vd[1]; a2 += e * vd[2]; a3 += e * vd[3];
        a4 += e * vd[4]; a5 += e * vd[5]; a6 += e * vd[6]; a7 += e * vd[7];
    }
    float inv = 1.f / l;
    u16* op = h + ((long)((b * SS + sq) * NNODE) + n0 + nl) * HIDN + hd * 8;
    *(uint4*)op = make_uint4(pk2(a0*inv, a1*inv), pk2(a2*inv, a3*inv),
                             pk2(a4*inv, a5*inv), pk2(a6*inv, a7*inv));
}

// ---------------- output projection: bf16 h[:, S-1] @ raw WoutT + raw bout ---
__global__ void out_proj_kernel(const u16* __restrict__ h, const void* __restrict__ W,
                                const void* __restrict__ b, void* __restrict__ out,
                                const int* __restrict__ flagp) {
    int fl = (*flagp != 0);
    int t = blockIdx.x * blockDim.x + threadIdx.x;
    if (t >= BB * NNODE * 3) return;
    int c  = t % 3;
    int bn = t / 3;
    int n  = bn & (NNODE - 1);
    int bb = bn >> 9;
    const u16* hp = h + ((long)((bb * SS + (SS - 1)) * NNODE + n)) * HIDN;
    float a = ld(b, c, fl);
#pragma unroll
    for (int i = 0; i < HIDN; i += 8) {
        uint4 hv = *(const uint4*)&hp[i];
        const u32 hw[4] = {hv.x, hv.y, hv.z, hv.w};
#pragma unroll
        for (int j2 = 0; j2 < 4; ++j2) {
            float hlo = b2f((u16)(hw[j2] & 0xFFFF));
            float hhi = b2f((u16)(hw[j2] >> 16));
            a += hlo * ld(W, c * 64 + i + j2 * 2,     fl)
               + hhi * ld(W, c * 64 + i + j2 * 2 + 1, fl);
        }
    }
    if (fl) ((float*)out)[t] = a;
    else    ((__hip_bfloat16*)out)[t] = __float2bfloat16(a);
}

extern "C" void kernel_launch(void* const* d_in, const int* in_sizes, int n_in,
                              void* d_out, int out_size, void* d_ws, size_t ws_size,
                              hipStream_t stream) {
    const int* ei = (const int*)d_in[1];

    float* ws = (float*)d_ws;
    int*   flag    = (int*)ws;                    // 64 floats reserved
    int*   row_ptr = (int*)(ws + 64);             // 513 ints (reserve 576)
    u16*   col_idx = (u16*)(ws + 640);            // 8192 u16 (4096 float slots)
    u16*   wb16  = (u16*)(ws + 4736);             // temporal pack: 24576 u16 (12288 fl)
    u16*   whd16 = (u16*)(ws + 4736 + 12288);     // spatial per-head: 32768 u16 (16384 fl)
    float* bsp   = ws + 4736 + 12288 + 16384;     // 2*192
    float* btp   = bsp + 384;                     // 2*192
    u16*   hb16  = (u16*)(btp + 384);             // ROWS*64 u16
    u16*   h2b16 = hb16 + ROWS * HIDN;            // ROWS*64 u16

    // dtype from host-visible byte sizes; runtime-detect only if ambiguous
    int flv = -1;
    if (in_sizes) {
        if (in_sizes[0] == XELEMS * 2) flv = 0;        // bf16
        else if (in_sizes[0] == XELEMS * 4) flv = 1;   // fp32
    }
    if (flv >= 0) {
        (void)hipMemsetAsync(flag, flv, sizeof(int), stream);
    } else {
        (void)hipMemsetAsync(flag, 0, sizeof(int), stream);
        detect_kernel<<<64, 256, 0, stream>>>((const u16*)d_in[0], flag);
    }

    PrepArgs pr;
    pr.x = d_in[0]; pr.Win = d_in[2]; pr.bin = d_in[3]; pr.h = hb16;
    pr.Wq[0] = d_in[4];  pr.bq[0] = d_in[5];
    pr.Wk[0] = d_in[6];  pr.bk[0] = d_in[7];
    pr.Wv[0] = d_in[8];  pr.bv[0] = d_in[9];
    pr.Wq[1] = d_in[10]; pr.bq[1] = d_in[11];
    pr.Wk[1] = d_in[12]; pr.bk[1] = d_in[13];
    pr.Wv[1] = d_in[14]; pr.bv[1] = d_in[15];
    pr.wb = wb16; pr.whd = whd16; pr.bp[0] = bsp; pr.bp[1] = btp;
    pr.ei = ei; pr.row_ptr = row_ptr; pr.col_idx = col_idx;
    prep_kernel<<<384 + 48 + 64 + 1, 512, 0, stream>>>(pr, flag);

    for (int l = 0; l < NLAY; ++l) {
        spat_fused_kernel<<<BB * SS * NHEADS * 2, 256, 0, stream>>>(
            hb16, whd16 + l * 16384, bsp + l * 192, row_ptr, col_idx, h2b16);
        temp_fused_kernel<<<BB * (NNODE / 4), 384, 0, stream>>>(
            h2b16, wb16 + l * 12288, btp + l * 192, hb16);
    }
    out_proj_kernel<<<(BB * NNODE * 3 + 255) / 256, 256, 0, stream>>>(
        hb16, d_in[16], d_in[17], d_out, flag);
}

// Round 14
// 171.570 us; speedup vs baseline: 1.9372x; 1.0674x over previous
//
#include <hip/hip_runtime.h>
#include <hip/hip_bf16.h>

#define HIDN   64
#define NHEADS 8
#define DHEAD  8
#define NLAY   2
#define BB     4
#define SS     12
#define NNODE  512
#define NEDGE  8192
#define XELEMS (BB * SS * NNODE * 3)      // 73728
#define ROWS   (BB * SS * NNODE)          // 24576
#define QSCALE 0.51006967f                // (1/sqrt(8)) * log2(e): exp(x)=exp2(x*log2e)

typedef unsigned short u16;
typedef unsigned int   u32;
typedef __attribute__((ext_vector_type(4))) float f4;   // indexable float4
typedef __attribute__((ext_vector_type(8))) short s8v;  // 8 bf16 (4 VGPRs)

__device__ __forceinline__ float b2f(u16 u) {
    union { u32 i; float f; } c; c.i = ((u32)u) << 16; return c.f;
}
__device__ __forceinline__ u16 f2b(float f) {   // RNE float->bf16 bits
    union { float f; u32 i; } c; c.f = f;
    u32 r = c.i + 0x7FFFu + ((c.i >> 16) & 1u);
    return (u16)(r >> 16);
}
__device__ __forceinline__ u32 pk2(float a, float b) {
    return (u32)f2b(a) | ((u32)f2b(b) << 16);
}
// decode element i of a raw input tensor (fl=1 -> fp32, fl=0 -> bf16)
__device__ __forceinline__ float ld(const void* p, int i, int fl) {
    return fl ? ((const float*)p)[i] : b2f(((const u16*)p)[i]);
}

// -------- dtype detection FALLBACK (only if in_sizes is ambiguous) -----------
__global__ void detect_kernel(const u16* __restrict__ x, int* __restrict__ flag) {
    int i0 = blockIdx.x * 256 + threadIdx.x;
    int bad = 0;
    for (int i = i0; i < XELEMS; i += 64 * 256) {
        float v = fabsf(b2f(x[i]));
        if (!(v <= 100.f)) bad = 1;   // catches huge AND NaN
    }
    if (bad) atomicOr(flag, 1);       // flag=1 -> inputs are fp32
}

// ---------------- PREP: input_proj(bf16) + W packs(bf16) + mask/CSR ----------
// wb (temporal): [l][j 0..191][i 0..63] bf16 (B-frag loads 16B contiguous).
// whd (spatial, per-head): [l][hd][tile2][c 0..15][i 0..63] bf16;
//   tile0 cols = [Wk col hd*8+c | Wv col hd*8+(c-8)], tile1 = [Wq | zeros].
struct PrepArgs {
    const void* x; const void* Win; const void* bin; u16* h;
    const void* Wq[2]; const void* bq[2];
    const void* Wk[2]; const void* bk[2];
    const void* Wv[2]; const void* bv[2];
    u16* wb; u16* whd; float* bp[2];
    const int* ei; int* row_ptr; u16* col_idx;
};
__global__ __launch_bounds__(512) void prep_kernel(PrepArgs a, const int* __restrict__ flagp) {
    __shared__ u32 msk[NNODE * 16];   // 32 KB (only used by last block)
    __shared__ int sc[512];
    int fl = (*flagp != 0);
    int bid = blockIdx.x;
    int tid = threadIdx.x;
    if (bid < 384) {
        // ---- input projection: 8 consecutive h elems per thread, bf16 out
        int base = (bid * 512 + tid) * 8;     // row*64 + j0
        int row = base >> 6, j0 = base & 63;
        float x0 = ld(a.x, row * 3, fl);
        float x1 = ld(a.x, row * 3 + 1, fl);
        float x2 = ld(a.x, row * 3 + 2, fl);
        float o[8];
#pragma unroll
        for (int jj = 0; jj < 8; ++jj) {
            int j = j0 + jj;
            o[jj] = ld(a.bin, j, fl) + x0 * ld(a.Win, j * 3, fl)
                  + x1 * ld(a.Win, j * 3 + 1, fl) + x2 * ld(a.Win, j * 3 + 2, fl);
        }
        *(uint4*)&a.h[base] = make_uint4(pk2(o[0], o[1]), pk2(o[2], o[3]),
                                         pk2(o[4], o[5]), pk2(o[6], o[7]));
        return;
    }
    if (bid < 432) {
        // ---- temporal W full pack (p=1): dest l*12288 + j*64 + i
        int u = (bid - 384) * 512 + tid;  // 0..24575
        int l = u / 12288;
        int t = u - l * 12288;
        int j = t >> 6, i = t & 63;
        int cg = j >> 6, cc = j & 63;
        const void* W = (cg == 0) ? a.Wq[1] : (cg == 1) ? a.Wk[1] : a.Wv[1];
        a.wb[u] = f2b(ld(W, l * 4096 + cc * 64 + i, fl));
        // ---- bias (both p): first 768 u's cover 2p x 2l x 192
        if (u < 768) {
            int p2 = u / 384;
            int r3 = u - p2 * 384;
            int l2 = r3 / 192;
            int j2 = r3 - l2 * 192;
            int cg2 = j2 >> 6;
            const void* B = (cg2 == 0) ? a.bq[p2] : (cg2 == 1) ? a.bk[p2] : a.bv[p2];
            a.bp[p2][l2 * 192 + j2] = ld(B, l2 * 64 + (j2 & 63), fl);
        }
        return;
    }
    if (bid < 496) {
        // ---- spatial per-head pack: u -> [l][hd][tile][c][i]
        int u = (bid - 432) * 512 + tid;  // 0..32767
        int l    = u >> 14;
        int rem  = u & 16383;
        int hd   = rem >> 11;
        int rem2 = rem & 2047;
        int tile = rem2 >> 10;
        int rem3 = rem2 & 1023;
        int c    = rem3 >> 6;
        int i    = rem3 & 63;
        int j;
        if (tile == 0) j = (c < 8) ? (64 + hd * 8 + c) : (128 + hd * 8 + (c - 8));
        else           j = (c < 8) ? (hd * 8 + c) : -1;
        u16 val = 0;
        if (j >= 0) {
            int cg = j >> 6, cc = j & 63;
            const void* W = (cg == 0) ? a.Wq[0] : (cg == 1) ? a.Wk[0] : a.Wv[0];
            val = f2b(ld(W, l * 4096 + cc * 64 + i, fl));
        }
        a.whd[u] = val;
        return;
    }
    // ---- mask bitset (LDS) + CSR build, one 512-thread block
    for (int i = tid; i < NNODE * 16; i += 512) msk[i] = 0;
    __syncthreads();
    for (int e = tid; e < NEDGE; e += 512) {
        int r = a.ei[e];           // query row
        int m = a.ei[NEDGE + e];   // key col
        atomicOr(&msk[r * 16 + (m >> 5)], 1u << (m & 31));
    }
    __syncthreads();
    int n = tid;   // 0..511
    u32 w[16];
    int d = 0;
#pragma unroll
    for (int i = 0; i < 16; ++i) { w[i] = msk[n * 16 + i]; d += __popc(w[i]); }
    sc[n] = d;
    __syncthreads();
    for (int s = 1; s < 512; s <<= 1) {
        int v = (n >= s) ? sc[n - s] : 0;
        __syncthreads();
        sc[n] += v;
        __syncthreads();
    }
    int excl = sc[n] - d;
    a.row_ptr[n] = excl;
    if (n == 511) a.row_ptr[512] = sc[511];
    int base = excl;
#pragma unroll
    for (int i = 0; i < 16; ++i) {
        u32 m = w[i];
        while (m) {
            int b = __ffs(m) - 1;
            m &= m - 1;
            a.col_idx[base++] = (u16)(i * 32 + b);
        }
    }
}

// ---------------- FUSED spatial v2: dedup K/V GEMM, one block per pair -------
// grid 384 = pair (bs*8+hd); 512 thr (8 waves). K/V computed ONCE (was 2x
// across halves). Per wave: 4 KV row-tiles x2 MFMA + 4 q row-tiles x2 MFMA.
// C (m89 mapping, R11/R13-HW-proven) -> Ks/Vs[512][8], qS[512][9] LDS.
// ONE barrier, then R8 sparse-CSR attention over all 512 queries (n = tid).
// Same fragments/bias/MFMA order as R13 -> bit-identical values.
__global__ __launch_bounds__(512) void spat_fused_kernel(
    const u16* __restrict__ hb, const u16* __restrict__ whd,
    const float* __restrict__ bp,
    const int* __restrict__ row_ptr, const u16* __restrict__ col_idx,
    u16* __restrict__ h2) {
    __shared__ __align__(16) float Ks[NNODE][8];   // 16 KB
    __shared__ __align__(16) float Vs[NNODE][8];   // 16 KB
    __shared__ float qS[NNODE][9];                 // 18 KB
    int pair = blockIdx.x;
    int bs = pair >> 3, hd = pair & 7;      // bs = b*S+s in [0,48)
    int t = threadIdx.x;
    int lane = t & 63, wv = t >> 6;         // 8 waves
    int lrow = lane & 15, kg = lane >> 4;
    const u16* hsl = hb + (long)bs * NNODE * HIDN;
    const u16* wkv = whd + hd * 2048;            // tile0: [k8|v8]
    const u16* wq  = whd + hd * 2048 + 1024;     // tile1: [q8|0]
    s8v bkv0 = *(const s8v*)(wkv + lrow * 64 + kg * 8);
    s8v bkv1 = *(const s8v*)(wkv + lrow * 64 + kg * 8 + 32);
    s8v bq0  = *(const s8v*)(wq  + lrow * 64 + kg * 8);
    s8v bq1  = *(const s8v*)(wq  + lrow * 64 + kg * 8 + 32);
    float biasKV = (lrow < 8) ? bp[64 + hd * 8 + lrow] : bp[128 + hd * 8 + (lrow & 7)];
    float biasQ  = bp[hd * 8 + (lrow & 7)];
    // K/V GEMM: 4 row-tiles per wave (8 waves cover all 32 tiles = 512 nodes)
#pragma unroll
    for (int s = 0; s < 4; ++s) {
        int rt = wv * 4 + s;                 // 0..31
        const u16* ap = hsl + (rt * 16 + lrow) * 64 + kg * 8;
        s8v ha0 = *(const s8v*)ap;
        s8v ha1 = *(const s8v*)(ap + 32);
        f4 acc = (f4){0.f, 0.f, 0.f, 0.f};
        acc = __builtin_amdgcn_mfma_f32_16x16x32_bf16(ha0, bkv0, acc, 0, 0, 0);
        acc = __builtin_amdgcn_mfma_f32_16x16x32_bf16(ha1, bkv1, acc, 0, 0, 0);
        int node = rt * 16 + kg * 4;
        if (lrow < 8) {
#pragma unroll
            for (int r = 0; r < 4; ++r) Ks[node + r][lrow] = acc[r] + biasKV;
        } else {
#pragma unroll
            for (int r = 0; r < 4; ++r) Vs[node + r][lrow & 7] = acc[r] + biasKV;
        }
    }
    // q GEMM: 4 row-tiles per wave (covers all 512 query rows)
#pragma unroll
    for (int s = 0; s < 4; ++s) {
        int rt = wv * 4 + s;                 // 0..31
        const u16* ap = hsl + (rt * 16 + lrow) * 64 + kg * 8;
        s8v ha0 = *(const s8v*)ap;
        s8v ha1 = *(const s8v*)(ap + 32);
        f4 acc = (f4){0.f, 0.f, 0.f, 0.f};
        acc = __builtin_amdgcn_mfma_f32_16x16x32_bf16(ha0, bq0, acc, 0, 0, 0);
        acc = __builtin_amdgcn_mfma_f32_16x16x32_bf16(ha1, bq1, acc, 0, 0, 0);
        if (lrow < 8) {
            int nl = rt * 16 + kg * 4;
#pragma unroll
            for (int r = 0; r < 4; ++r) qS[nl + r][lrow] = (acc[r] + biasQ) * QSCALE;
        }
    }
    __syncthreads();
    // ---- sparse attention (R8-proven), n = tid over all 512 queries ----
    int n = t;
    float4 qa = make_float4(qS[n][0], qS[n][1], qS[n][2], qS[n][3]);
    float4 qc = make_float4(qS[n][4], qS[n][5], qS[n][6], qS[n][7]);
    int e0 = row_ptr[n], e1 = row_ptr[n + 1];
    float l = 0.f;
    float o0=0.f,o1=0.f,o2=0.f,o3=0.f,o4=0.f,o5=0.f,o6=0.f,o7=0.f;
    for (int e = e0; e < e1; ++e) {
        int m = col_idx[e];
        float4 ka = *(const float4*)&Ks[m][0];
        float4 kc = *(const float4*)&Ks[m][4];
        float s = qa.x*ka.x + qa.y*ka.y + qa.z*ka.z + qa.w*ka.w
                + qc.x*kc.x + qc.y*kc.y + qc.z*kc.z + qc.w*kc.w;
        float p = exp2f(s);          // q prescaled by (1/sqrt8)*log2e
        l += p;
        float4 va = *(const float4*)&Vs[m][0];
        float4 vc = *(const float4*)&Vs[m][4];
        o0 += p*va.x; o1 += p*va.y; o2 += p*va.z; o3 += p*va.w;
        o4 += p*vc.x; o5 += p*vc.y; o6 += p*vc.z; o7 += p*vc.w;
    }
    if (e1 == e0) {                  // fully-masked row: uniform mean(V)
        for (int m = 0; m < NNODE; ++m) {
            o0 += Vs[m][0]; o1 += Vs[m][1]; o2 += Vs[m][2]; o3 += Vs[m][3];
            o4 += Vs[m][4]; o5 += Vs[m][5]; o6 += Vs[m][6]; o7 += Vs[m][7];
        }
        l = (float)NNODE;
    }
    float inv = 1.f / l;
    u16* op = h2 + ((long)(bs * NNODE + n)) * HIDN + hd * 8;
    *(uint4*)op = make_uint4(pk2(o0*inv, o1*inv), pk2(o2*inv, o3*inv),
                             pk2(o4*inv, o5*inv), pk2(o6*inv, o7*inv));
}

// ---------------- FUSED temporal: MFMA qkv + attn (+ out_proj when last) -----
// grid 512 = (b, 4-node chunk); 384 thr (6 waves). Same structure as R13.
// When last=1: sq==11 threads stash their PACKED bf16 output words in LDS;
// after a barrier 12 threads compute the 3-col out projection with the EXACT
// decode+accumulate order of the old out_proj_kernel -> bit-identical output.
__global__ __launch_bounds__(384) void temp_fused_kernel(
    const u16* __restrict__ h2b, const u16* __restrict__ wb,
    const float* __restrict__ bp, u16* __restrict__ h,
    const void* __restrict__ Wout, const void* __restrict__ bout,
    void* __restrict__ out, const int* __restrict__ flagp, int last) {
    __shared__ float S[3][SS][32][9];   // 41472 B
    __shared__ u32 outS[4][32];         // packed bf16 pairs of last-step rows
    int b  = blockIdx.x >> 7;
    int n0 = (blockIdx.x & 127) * 4;
    int t = threadIdx.x;
    int lane = t & 63, wv = t >> 6;     // 6 waves
    int lrow = lane & 15, kg = lane >> 4;
    int rt  = wv >> 1;                  // 0..2
    int ct0 = (wv & 1) * 6;
    // A-frags: row gr = rt*16 + lrow -> (tt = gr>>2, nl = gr&3)
    int gr = rt * 16 + lrow;
    int tta = gr >> 2, nla = gr & 3;
    const u16* ap = h2b + ((long)((b * SS + tta) * NNODE) + n0 + nla) * HIDN + kg * 8;
    s8v haf0 = *(const s8v*)ap;
    s8v haf1 = *(const s8v*)(ap + 32);
#pragma unroll
    for (int s = 0; s < 6; ++s) {
        int ct = ct0 + s;
        const u16* wp = wb + (ct * 16 + lrow) * 64 + kg * 8;
        s8v wb0 = *(const s8v*)wp;
        s8v wb1 = *(const s8v*)(wp + 32);
        f4 acc = (f4){0.f, 0.f, 0.f, 0.f};
        acc = __builtin_amdgcn_mfma_f32_16x16x32_bf16(haf0, wb0, acc, 0, 0, 0);
        acc = __builtin_amdgcn_mfma_f32_16x16x32_bf16(haf1, wb1, acc, 0, 0, 0);
        int j = ct * 16 + lrow;
        float bb = bp[j];
        int tz = j >> 6, cc = j & 63, hd2 = cc >> 3, dh = cc & 7;
#pragma unroll
        for (int r = 0; r < 4; ++r) {
            int gr2 = rt * 16 + kg * 4 + r;
            S[tz][gr2 >> 2][(gr2 & 3) * 8 + hd2][dh] = acc[r] + bb;
        }
    }
    __syncthreads();
    // ---- temporal attention (R8-v4-proven) ----
    int sq = t >> 5, r = t & 31;        // r = nl*8+hd
    int nl = r >> 3, hd = r & 7;
    const float* qd = &S[0][sq][r][0];
    float q0=qd[0],q1=qd[1],q2=qd[2],q3=qd[3],q4=qd[4],q5=qd[5],q6=qd[6],q7=qd[7];
    float s[SS];
#pragma unroll
    for (int tt = 0; tt < SS; ++tt) {
        const float* kd = &S[1][tt][r][0];
        s[tt] = (q0 * kd[0] + q1 * kd[1] + q2 * kd[2] + q3 * kd[3] +
                 q4 * kd[4] + q5 * kd[5] + q6 * kd[6] + q7 * kd[7]) * QSCALE;
    }
    float mx = s[0];
#pragma unroll
    for (int tt = 1; tt < SS; ++tt) mx = fmaxf(mx, s[tt]);
    float l = 0.f;
#pragma unroll
    for (int tt = 0; tt < SS; ++tt) { s[tt] = exp2f(s[tt] - mx); l += s[tt]; }
    float a0=0.f,a1=0.f,a2=0.f,a3=0.f,a4=0.f,a5=0.f,a6=0.f,a7=0.f;
#pragma unroll
    for (int tt = 0; tt < SS; ++tt) {
        const float* vd = &S[2][tt][r][0];
        float e = s[tt];
        a0 += e * vd[0]; a1 += e * vd[1]; a2 += e * vd[2]; a3 += e * vd[3];
        a4 += e * vd[4]; a5 += e * vd[5]; a6 += e * vd[6]; a7 += e * vd[7];
    }
    float inv = 1.f / l;
    u32 p0 = pk2(a0*inv, a1*inv), p1 = pk2(a2*inv, a3*inv);
    u32 p2 = pk2(a4*inv, a5*inv), p3 = pk2(a6*inv, a7*inv);
    u16* op = h + ((long)((b * SS + sq) * NNODE) + n0 + nl) * HIDN + hd * 8;
    *(uint4*)op = make_uint4(p0, p1, p2, p3);
    // ---- fused out projection (last layer only) ----
    if (last) {
        if (sq == SS - 1) {
            outS[nl][hd * 4 + 0] = p0;
            outS[nl][hd * 4 + 1] = p1;
            outS[nl][hd * 4 + 2] = p2;
            outS[nl][hd * 4 + 3] = p3;
        }
        __syncthreads();
        if (t < 12) {
            int fl = (*flagp != 0);
            int c = t % 3, nl2 = t / 3;
            float acc = ld(bout, c, fl);
#pragma unroll
            for (int i = 0; i < HIDN; i += 8) {
                // same decode+accumulate order as old out_proj_kernel
                u32 hw0 = outS[nl2][i / 2 + 0];
                u32 hw1 = outS[nl2][i / 2 + 1];
                u32 hw2 = outS[nl2][i / 2 + 2];
                u32 hw3 = outS[nl2][i / 2 + 3];
                const u32 hw[4] = {hw0, hw1, hw2, hw3};
#pragma unroll
                for (int j2 = 0; j2 < 4; ++j2) {
                    float hlo = b2f((u16)(hw[j2] & 0xFFFF));
                    float hhi = b2f((u16)(hw[j2] >> 16));
                    acc += hlo * ld(Wout, c * 64 + i + j2 * 2,     fl)
                         + hhi * ld(Wout, c * 64 + i + j2 * 2 + 1, fl);
                }
            }
            int ti = (b * NNODE + n0 + nl2) * 3 + c;
            if (fl) ((float*)out)[ti] = acc;
            else    ((__hip_bfloat16*)out)[ti] = __float2bfloat16(acc);
        }
    }
}

extern "C" void kernel_launch(void* const* d_in, const int* in_sizes, int n_in,
                              void* d_out, int out_size, void* d_ws, size_t ws_size,
                              hipStream_t stream) {
    const int* ei = (const int*)d_in[1];

    float* ws = (float*)d_ws;
    int*   flag    = (int*)ws;                    // 64 floats reserved
    int*   row_ptr = (int*)(ws + 64);             // 513 ints (reserve 576)
    u16*   col_idx = (u16*)(ws + 640);            // 8192 u16 (4096 float slots)
    u16*   wb16  = (u16*)(ws + 4736);             // temporal pack: 24576 u16 (12288 fl)
    u16*   whd16 = (u16*)(ws + 4736 + 12288);     // spatial per-head: 32768 u16 (16384 fl)
    float* bsp   = ws + 4736 + 12288 + 16384;     // 2*192
    float* btp   = bsp + 384;                     // 2*192
    u16*   hb16  = (u16*)(btp + 384);             // ROWS*64 u16
    u16*   h2b16 = hb16 + ROWS * HIDN;            // ROWS*64 u16

    // dtype from host-visible byte sizes; runtime-detect only if ambiguous
    int flv = -1;
    if (in_sizes) {
        if (in_sizes[0] == XELEMS * 2) flv = 0;        // bf16
        else if (in_sizes[0] == XELEMS * 4) flv = 1;   // fp32
    }
    if (flv >= 0) {
        (void)hipMemsetAsync(flag, flv, sizeof(int), stream);
    } else {
        (void)hipMemsetAsync(flag, 0, sizeof(int), stream);
        detect_kernel<<<64, 256, 0, stream>>>((const u16*)d_in[0], flag);
    }

    PrepArgs pr;
    pr.x = d_in[0]; pr.Win = d_in[2]; pr.bin = d_in[3]; pr.h = hb16;
    pr.Wq[0] = d_in[4];  pr.bq[0] = d_in[5];
    pr.Wk[0] = d_in[6];  pr.bk[0] = d_in[7];
    pr.Wv[0] = d_in[8];  pr.bv[0] = d_in[9];
    pr.Wq[1] = d_in[10]; pr.bq[1] = d_in[11];
    pr.Wk[1] = d_in[12]; pr.bk[1] = d_in[13];
    pr.Wv[1] = d_in[14]; pr.bv[1] = d_in[15];
    pr.wb = wb16; pr.whd = whd16; pr.bp[0] = bsp; pr.bp[1] = btp;
    pr.ei = ei; pr.row_ptr = row_ptr; pr.col_idx = col_idx;
    prep_kernel<<<384 + 48 + 64 + 1, 512, 0, stream>>>(pr, flag);

    for (int l = 0; l < NLAY; ++l) {
        spat_fused_kernel<<<BB * SS * NHEADS, 512, 0, stream>>>(
            hb16, whd16 + l * 16384, bsp + l * 192, row_ptr, col_idx, h2b16);
        temp_fused_kernel<<<BB * (NNODE / 4), 384, 0, stream>>>(
            h2b16, wb16 + l * 12288, btp + l * 192, hb16,
            d_in[16], d_in[17], d_out, flag, (l == NLAY - 1) ? 1 : 0);
    }
}